// Round 5
// baseline (444.401 us; speedup 1.0000x reference)
//
#include <hip/hip_runtime.h>
#include <math.h>

#define NN 80
#define MITERS 50
#define NTHREADS 1024

typedef _Float16 h8 __attribute__((ext_vector_type(8)));
typedef float f4 __attribute__((ext_vector_type(4)));

__device__ __forceinline__ unsigned pk_mul_f16(unsigned a, unsigned b) {
  unsigned d; asm("v_pk_mul_f16 %0, %1, %2" : "=v"(d) : "v"(a), "v"(b)); return d;
}
__device__ __forceinline__ unsigned pk_max_f16(unsigned a, unsigned b) {
  unsigned d; asm("v_pk_max_f16 %0, %1, %2" : "=v"(d) : "v"(a), "v"(b)); return d;
}
__device__ __forceinline__ h8 as_h8(uint4 u) {
  union { uint4 u; h8 h; } x; x.u = u; return x.h;
}

// ---- LDS byte offsets (16B-aligned) ----
// XH/TT: paired fp16 (quad-row blocks of 656B); MM: 4 bufs of fp16 [80][104]
// SRCH: fp16 [80][104] (0/1); DLT: f32 [a][84]
#define OFF_XH    0
#define OFF_TT    13120
#define OFF_MM    26240          // 4 * 16640 = 66560
#define OFF_SRCH  92800
#define OFF_DLT   109440
#define OFF_FR    136320
#define OFF_FA    136640
#define OFF_RD    136960
#define OFF_AD    137280
#define OFF_WSUM  137600         // 2 x 16 f32 double-buffered
#define OFF_LSUM  137728         // 16 f32
#define LDS_BYTES 137792         // 134.6 KiB < 160 KiB

// paired fp16 byte index for element [r][k] of an 80x80 matrix
#define PB(r, k) ((((r) >> 2) * 656) + (((k) >> 1) * 16) + (((r) & 3) * 4) + (((k) & 1) * 2))

// one MFMA C-tile of phase B: C[I0..+16][A0..+16] = SRC @ max4(MM0..MM3)
#define DO_TILE(I0, A0, AF, XO)                                               \
  {                                                                           \
    f4 acc = {0.f, 0.f, 0.f, 0.f};                                            \
    _Pragma("unroll")                                                         \
    for (int ks = 0; ks < 3; ++ks) {                                          \
      const int mo = ((A0) + la) * 208 + ks * 64 + gr * 16;                   \
      const uint4 b0 = *(const uint4*)(MMb + mo);                             \
      const uint4 b1 = *(const uint4*)(MMb + 16640 + mo);                     \
      const uint4 b2 = *(const uint4*)(MMb + 33280 + mo);                     \
      const uint4 b3 = *(const uint4*)(MMb + 49920 + mo);                     \
      uint4 bb;                                                               \
      bb.x = pk_max_f16(pk_max_f16(b0.x, b1.x), pk_max_f16(b2.x, b3.x));      \
      bb.y = pk_max_f16(pk_max_f16(b0.y, b1.y), pk_max_f16(b2.y, b3.y));      \
      bb.z = pk_max_f16(pk_max_f16(b0.z, b1.z), pk_max_f16(b2.z, b3.z));      \
      bb.w = pk_max_f16(pk_max_f16(b0.w, b1.w), pk_max_f16(b2.w, b3.w));      \
      acc = __builtin_amdgcn_mfma_f32_16x16x32_f16(as_h8(AF[ks]),             \
                                                   as_h8(bb), acc, 0, 0, 0);  \
    }                                                                         \
    const int col = (A0) + la;                                                \
    const int rb = (I0) + gr * 4;                                             \
    const float4 dl = *(const float4*)(DLTb + col * 336 + rb * 4);            \
    const float n0 = fmaf(XO[0], dl.x, acc[0]) * inv;                         \
    const float n1 = fmaf(XO[1], dl.y, acc[1]) * inv;                         \
    const float n2 = fmaf(XO[2], dl.z, acc[2]) * inv;                         \
    const float n3 = fmaf(XO[3], dl.w, acc[3]) * inv;                         \
    ss += n0 * n0 + n1 * n1 + n2 * n2 + n3 * n3;                              \
    XO[0] = n0; XO[1] = n1; XO[2] = n2; XO[3] = n3;                           \
    char* xa = XHb + (((I0) >> 2) + gr) * 656 + (col >> 1) * 16 + (col & 1) * 2; \
    *(_Float16*)(xa) = (_Float16)n0;                                          \
    *(_Float16*)(xa + 4) = (_Float16)n1;                                      \
    *(_Float16*)(xa + 8) = (_Float16)n2;                                      \
    *(_Float16*)(xa + 12) = (_Float16)n3;                                     \
  }

__global__ void __launch_bounds__(NTHREADS)
grf_kernel(const float* __restrict__ recon, const float* __restrict__ adj,
           float* __restrict__ out) {
  extern __shared__ char ldsb[];
  char* XHb = ldsb + OFF_XH;
  char* TTb = ldsb + OFF_TT;
  char* MMb = ldsb + OFF_MM;
  char* SRCHb = ldsb + OFF_SRCH;
  char* DLTb = ldsb + OFF_DLT;
  float* FR = (float*)(ldsb + OFF_FR);
  float* FA = (float*)(ldsb + OFF_FA);
  float* RD = (float*)(ldsb + OFF_RD);
  float* AD = (float*)(ldsb + OFF_AD);
  float* WSUM = (float*)(ldsb + OFF_WSUM);
  float* LSUM = (float*)(ldsb + OFF_LSUM);

  const int t = threadIdx.x;
  const int wave = t >> 6, lane = t & 63;
  const int la = lane & 15, gr = lane >> 4;

  // ---- row sums + diagonals ----
  if (t < 80) {
    float s = 0.f;
    for (int b = 0; b < NN; ++b) s += recon[t * NN + b];
    FR[t] = s;
    RD[t] = recon[t * NN + t];
  } else if (t < 160) {
    const int i = t - 80;
    float s = 0.f;
    for (int j = 0; j < NN; ++j) s += adj[i * NN + j];
    FA[i] = s;
    AD[i] = adj[i * NN + i];
  }
  if (t < 32) {
    const float q = (float)(_Float16)(1.0f / 80.0f);
    WSUM[t] = (t == 0) ? 6400.0f * q * q : 0.f;  // ||quantized x0||^2
  }
  __syncthreads();

  // ---- fill operand arrays + BCE loss over triu ----
  float lacc = 0.f;
  for (int f = t; f < NN * NN; f += NTHREADS) {
    const int r = f / NN, c = f - (f / NN) * NN;
    *(_Float16*)(XHb + PB(r, c)) = (_Float16)(1.0f / 80.0f);        // x0[i=r][a=c]
    const float tv = (r == c) ? 0.f : recon[r * NN + c] * RD[r] * RD[c];
    *(_Float16*)(TTb + PB(r, c)) = (_Float16)tv;                    // tgt[a=r][b=c]
    *(float*)(DLTb + (c * 84 + r) * 4) =
        AD[r] * RD[c] / (fabsf(FA[r] - FR[c]) + 1.f);               // DLT[a=c][i=r]
    const float sv = (r == c) ? 0.f : adj[r * NN + c] * AD[r] * AD[c];
    *(_Float16*)(SRCHb + (r * 104 + c) * 2) = (_Float16)sv;         // SRCH[i=r][j=c]
    if (c >= r) {
      const float tb = adj[f], p = recon[f];
      lacc -= tb * logf(p) + (1.f - tb) * logf(1.f - p);
    }
  }
  // zero pads: SRCH j in [80,104); all 4 MM buffers (16640 u32)
  for (int f = t; f < 1920; f += NTHREADS) {
    const int r = f / 24, j = 80 + (f - (f / 24) * 24);
    *(_Float16*)(SRCHb + (r * 104 + j) * 2) = (_Float16)0.f;
  }
  for (int f = t; f < 16640; f += NTHREADS) *(unsigned*)(MMb + f * 4) = 0u;

  #pragma unroll
  for (int off = 32; off > 0; off >>= 1) lacc += __shfl_down(lacc, off, 64);
  if (lane == 0) LSUM[wave] = lacc;
  __syncthreads();
  if (t == 0) {
    float s = 0.f;
    for (int w = 0; w < 16; ++w) s += LSUM[w];
    out[0] = s / 3240.f;  // 80*81/2
  }

  // ---- per-wave persistent SRC A-fragments ----
  const int i00 = (wave / 5) * 16, a00 = (wave % 5) * 16;
  const int tt1 = wave + 16;
  const bool has2 = tt1 < 25;
  const int i01 = has2 ? (tt1 / 5) * 16 : 0;
  const int a01 = has2 ? (tt1 % 5) * 16 : 0;
  uint4 af0[3], af1[3];
  af1[0] = af1[1] = af1[2] = make_uint4(0u, 0u, 0u, 0u);
  #pragma unroll
  for (int ks = 0; ks < 3; ++ks)
    af0[ks] = *(const uint4*)(SRCHb + (i00 + la) * 208 + ks * 64 + gr * 16);
  if (has2) {
    #pragma unroll
    for (int ks = 0; ks < 3; ++ks)
      af1[ks] = *(const uint4*)(SRCHb + (i01 + la) * 208 + ks * 64 + gr * 16);
  }

  // ---- phase-A mapping: 4 groups x 200 threads, 8x4 tiles, 20 b's each ----
  const int g = t >> 8;                 // b-quarter
  const int u = t & 255;
  const bool actA = (u < 200);
  const int rtA = u / 20;               // 0..9 (8-row j-tiles)
  const int ctA = u - rtA * 20;         // 0..19 (4-col a-tiles)
  const char* xbase = XHb + (2 * rtA) * 656 + g * 160;
  char* mwp = MMb + g * 16640 + (ctA * 4) * 208 + rtA * 16;

  // persistent tgt registers: 4 a-cols x 20 b (10 b-pairs) = 10 uint4
  uint4 tr[10];
  #pragma unroll
  for (int cc = 0; cc < 10; ++cc)
    tr[cc] = *(const uint4*)(TTb + ctA * 656 + (g * 10 + cc) * 16);

  // persistent x-old registers for phase B
  float xo0[4], xo1[4];
  #pragma unroll
  for (int k = 0; k < 4; ++k) xo0[k] = xo1[k] = (float)(_Float16)(1.0f / 80.0f);

  for (int it = 0; it < MITERS; ++it) {
    // ---- Phase A: MM_g[a][j] = max_{b in quarter} x[j,b]*tgt[a,b] ----
    if (actA) {
      unsigned m[8][4];
      #pragma unroll
      for (int r = 0; r < 8; ++r)
        #pragma unroll
        for (int c = 0; c < 4; ++c) m[r][c] = 0u;
      #pragma unroll 2
      for (int cc = 0; cc < 10; ++cc) {
        const uint4 x0 = *(const uint4*)(xbase + cc * 16);
        const uint4 x1 = *(const uint4*)(xbase + 656 + cc * 16);
        const unsigned xr[8] = {x0.x, x0.y, x0.z, x0.w, x1.x, x1.y, x1.z, x1.w};
        const unsigned tc[4] = {tr[cc].x, tr[cc].y, tr[cc].z, tr[cc].w};
        #pragma unroll
        for (int r = 0; r < 8; ++r)
          #pragma unroll
          for (int c = 0; c < 4; ++c)
            m[r][c] = pk_max_f16(m[r][c], pk_mul_f16(xr[r], tc[c]));
      }
      #pragma unroll
      for (int c = 0; c < 4; ++c) {
        unsigned lo[8];
        #pragma unroll
        for (int r = 0; r < 8; ++r) {
          const unsigned v = m[r][c];
          lo[r] = pk_max_f16(v, (v >> 16) | (v << 16)) & 0xffffu;  // fold b-pair
        }
        const uint4 w = make_uint4(lo[0] | (lo[1] << 16), lo[2] | (lo[3] << 16),
                                   lo[4] | (lo[5] << 16), lo[6] | (lo[7] << 16));
        *(uint4*)(mwp + c * 208) = w;
      }
    }
    __syncthreads();

    // ---- Phase B: x_new = inv * (x*d + SRC @ max4(MM)) via MFMA ----
    const float* WIN = WSUM + ((it & 1) << 4);
    const float4 wa = *(const float4*)(WIN);
    const float4 wb = *(const float4*)(WIN + 4);
    const float4 wc = *(const float4*)(WIN + 8);
    const float4 wd = *(const float4*)(WIN + 12);
    const float tot = ((wa.x + wa.y) + (wa.z + wa.w)) +
                      ((wb.x + wb.y) + (wb.z + wb.w)) +
                      ((wc.x + wc.y) + (wc.z + wc.w)) +
                      ((wd.x + wd.y) + (wd.z + wd.w));
    const float inv = 1.0f / sqrtf(tot);

    float ss = 0.f;
    DO_TILE(i00, a00, af0, xo0);
    if (has2) DO_TILE(i01, a01, af1, xo1);

    #pragma unroll
    for (int off = 32; off > 0; off >>= 1) ss += __shfl_down(ss, off, 64);
    if (lane == 0) WSUM[(((it + 1) & 1) << 4) + wave] = ss;
    __syncthreads();
  }

  // ---- exact final normalization + output (out[1 + i*80 + a]) ----
  {
    const float* WF = WSUM + ((MITERS & 1) << 4);
    float tot = 0.f;
    #pragma unroll
    for (int w = 0; w < 16; ++w) tot += WF[w];
    const float finv = 1.0f / sqrtf(tot);
    for (int f = t; f < NN * NN; f += NTHREADS) {
      const int i = f / NN, a = f - (f / NN) * NN;
      out[1 + f] = (float)*(const _Float16*)(XHb + PB(i, a)) * finv;
    }
  }
}

extern "C" void kernel_launch(void* const* d_in, const int* in_sizes, int n_in,
                              void* d_out, int out_size, void* d_ws, size_t ws_size,
                              hipStream_t stream) {
  const float* recon = (const float*)d_in[0];
  const float* adj   = (const float*)d_in[1];
  float* out = (float*)d_out;
  (void)in_sizes; (void)n_in; (void)out_size; (void)d_ws; (void)ws_size;

  hipFuncSetAttribute(reinterpret_cast<const void*>(grf_kernel),
                      hipFuncAttributeMaxDynamicSharedMemorySize, LDS_BYTES);
  grf_kernel<<<1, NTHREADS, LDS_BYTES, stream>>>(recon, adj, out);
}

// Round 6
// 443.791 us; speedup vs baseline: 1.0014x; 1.0014x over previous
//
#include <hip/hip_runtime.h>
#include <math.h>

#define NN 80
#define MITERS 50
#define NTHREADS 1024

typedef _Float16 h8 __attribute__((ext_vector_type(8)));
typedef float f4 __attribute__((ext_vector_type(4)));

__device__ __forceinline__ unsigned pk_mul_f16(unsigned a, unsigned b) {
  unsigned d; asm("v_pk_mul_f16 %0, %1, %2" : "=v"(d) : "v"(a), "v"(b)); return d;
}
__device__ __forceinline__ unsigned pk_max_f16(unsigned a, unsigned b) {
  unsigned d; asm("v_pk_max_f16 %0, %1, %2" : "=v"(d) : "v"(a), "v"(b)); return d;
}
__device__ __forceinline__ h8 as_h8(uint4 u) {
  union { uint4 u; h8 h; } x; x.u = u; return x.h;
}

// ---- LDS byte offsets (16B-aligned) ----
#define OFF_XH    0
#define OFF_TT    13120
#define OFF_MM    26240          // 4 * 16640 = 66560
#define OFF_SRCH  92800
#define OFF_DLT   109440
#define OFF_FR    136320
#define OFF_FA    136640
#define OFF_RD    136960
#define OFF_AD    137280
#define OFF_WSUM  137600         // 2 x 16 f32 double-buffered
#define OFF_LSUM  137728         // 16 f32
#define LDS_BYTES 137792         // 134.6 KiB < 160 KiB

// paired fp16 byte index for element [r][k] of an 80x80 matrix
#define PB(r, k) ((((r) >> 2) * 656) + (((k) >> 1) * 16) + (((r) & 3) * 4) + (((k) & 1) * 2))

// MM swizzle: 16B j-block L of row a lives at phys block L ^ ((a>>2)&3).
// Self-consistent: reads/writes both key on a; unwritten phys blocks are the
// zero pads (L in [10,13) logical <-> never-written phys), so pad reads stay 0.

// one MFMA C-tile of phase B: C[I0..+16][A0..+16] = SRC @ max4(MM0..MM3)
#define DO_TILE(I0, A0, AF, XO)                                               \
  {                                                                           \
    f4 acc = {0.f, 0.f, 0.f, 0.f};                                            \
    _Pragma("unroll")                                                         \
    for (int ks = 0; ks < 3; ++ks) {                                          \
      const int blk = (ks * 4 + gr) ^ mkey;                                   \
      const int mo = ((A0) + la) * 208 + blk * 16;                            \
      const uint4 b0 = *(const uint4*)(MMb + mo);                             \
      const uint4 b1 = *(const uint4*)(MMb + 16640 + mo);                     \
      const uint4 b2 = *(const uint4*)(MMb + 33280 + mo);                     \
      const uint4 b3 = *(const uint4*)(MMb + 49920 + mo);                     \
      uint4 bb;                                                               \
      bb.x = pk_max_f16(pk_max_f16(b0.x, b1.x), pk_max_f16(b2.x, b3.x));      \
      bb.y = pk_max_f16(pk_max_f16(b0.y, b1.y), pk_max_f16(b2.y, b3.y));      \
      bb.z = pk_max_f16(pk_max_f16(b0.z, b1.z), pk_max_f16(b2.z, b3.z));      \
      bb.w = pk_max_f16(pk_max_f16(b0.w, b1.w), pk_max_f16(b2.w, b3.w));      \
      acc = __builtin_amdgcn_mfma_f32_16x16x32_f16(as_h8(AF[ks]),             \
                                                   as_h8(bb), acc, 0, 0, 0);  \
    }                                                                         \
    const int col = (A0) + la;                                                \
    const int rb = (I0) + gr * 4;                                             \
    const float4 dl = *(const float4*)(DLTb + col * 336 + rb * 4);            \
    const float n0 = fmaf(XO[0], dl.x, acc[0]) * inv;                         \
    const float n1 = fmaf(XO[1], dl.y, acc[1]) * inv;                         \
    const float n2 = fmaf(XO[2], dl.z, acc[2]) * inv;                         \
    const float n3 = fmaf(XO[3], dl.w, acc[3]) * inv;                         \
    ss += n0 * n0 + n1 * n1 + n2 * n2 + n3 * n3;                              \
    XO[0] = n0; XO[1] = n1; XO[2] = n2; XO[3] = n3;                           \
    char* xa = XHb + (((I0) >> 2) + gr) * 656 + (col >> 1) * 16 + (col & 1) * 2; \
    *(_Float16*)(xa) = (_Float16)n0;                                          \
    *(_Float16*)(xa + 4) = (_Float16)n1;                                      \
    *(_Float16*)(xa + 8) = (_Float16)n2;                                      \
    *(_Float16*)(xa + 12) = (_Float16)n3;                                     \
  }

__global__ void __launch_bounds__(NTHREADS, 4)
grf_kernel(const float* __restrict__ recon, const float* __restrict__ adj,
           float* __restrict__ out) {
  extern __shared__ char ldsb[];
  char* XHb = ldsb + OFF_XH;
  char* TTb = ldsb + OFF_TT;
  char* MMb = ldsb + OFF_MM;
  char* SRCHb = ldsb + OFF_SRCH;
  char* DLTb = ldsb + OFF_DLT;
  float* FR = (float*)(ldsb + OFF_FR);
  float* FA = (float*)(ldsb + OFF_FA);
  float* RD = (float*)(ldsb + OFF_RD);
  float* AD = (float*)(ldsb + OFF_AD);
  float* WSUM = (float*)(ldsb + OFF_WSUM);
  float* LSUM = (float*)(ldsb + OFF_LSUM);

  const int t = threadIdx.x;
  const int wave = t >> 6, lane = t & 63;
  const int la = lane & 15, gr = lane >> 4;
  const int mkey = (la >> 2) & 3;  // MM read-side swizzle key

  // ---- row sums + diagonals ----
  if (t < 80) {
    float s = 0.f;
    for (int b = 0; b < NN; ++b) s += recon[t * NN + b];
    FR[t] = s;
    RD[t] = recon[t * NN + t];
  } else if (t < 160) {
    const int i = t - 80;
    float s = 0.f;
    for (int j = 0; j < NN; ++j) s += adj[i * NN + j];
    FA[i] = s;
    AD[i] = adj[i * NN + i];
  }
  if (t < 32) {
    const float q = (float)(_Float16)(1.0f / 80.0f);
    WSUM[t] = (t == 0) ? 6400.0f * q * q : 0.f;  // ||quantized x0||^2
  }
  __syncthreads();

  // ---- fill operand arrays + BCE loss over triu ----
  float lacc = 0.f;
  for (int f = t; f < NN * NN; f += NTHREADS) {
    const int r = f / NN, c = f - (f / NN) * NN;
    *(_Float16*)(XHb + PB(r, c)) = (_Float16)(1.0f / 80.0f);        // x0[i=r][a=c]
    const float tv = (r == c) ? 0.f : recon[r * NN + c] * RD[r] * RD[c];
    *(_Float16*)(TTb + PB(r, c)) = (_Float16)tv;                    // tgt[a=r][b=c]
    *(float*)(DLTb + (c * 84 + r) * 4) =
        AD[r] * RD[c] / (fabsf(FA[r] - FR[c]) + 1.f);               // DLT[a=c][i=r]
    const float sv = (r == c) ? 0.f : adj[r * NN + c] * AD[r] * AD[c];
    *(_Float16*)(SRCHb + (r * 104 + c) * 2) = (_Float16)sv;         // SRCH[i=r][j=c]
    if (c >= r) {
      const float tb = adj[f], p = recon[f];
      lacc -= tb * logf(p) + (1.f - tb) * logf(1.f - p);
    }
  }
  // zero pads: SRCH j in [80,104); all 4 MM buffers (16640 u32)
  for (int f = t; f < 1920; f += NTHREADS) {
    const int r = f / 24, j = 80 + (f - (f / 24) * 24);
    *(_Float16*)(SRCHb + (r * 104 + j) * 2) = (_Float16)0.f;
  }
  for (int f = t; f < 16640; f += NTHREADS) *(unsigned*)(MMb + f * 4) = 0u;

  #pragma unroll
  for (int off = 32; off > 0; off >>= 1) lacc += __shfl_down(lacc, off, 64);
  if (lane == 0) LSUM[wave] = lacc;
  __syncthreads();
  if (t == 0) {
    float s = 0.f;
    for (int w = 0; w < 16; ++w) s += LSUM[w];
    out[0] = s / 3240.f;  // 80*81/2
  }

  // ---- per-wave persistent SRC A-fragments ----
  const int i00 = (wave / 5) * 16, a00 = (wave % 5) * 16;
  const int tt1 = wave + 16;
  const bool has2 = tt1 < 25;
  const int i01 = has2 ? (tt1 / 5) * 16 : 0;
  const int a01 = has2 ? (tt1 % 5) * 16 : 0;
  uint4 af0[3], af1[3];
  af1[0] = af1[1] = af1[2] = make_uint4(0u, 0u, 0u, 0u);
  #pragma unroll
  for (int ks = 0; ks < 3; ++ks)
    af0[ks] = *(const uint4*)(SRCHb + (i00 + la) * 208 + ks * 64 + gr * 16);
  if (has2) {
    #pragma unroll
    for (int ks = 0; ks < 3; ++ks)
      af1[ks] = *(const uint4*)(SRCHb + (i01 + la) * 208 + ks * 64 + gr * 16);
  }

  // ---- phase-A mapping: 4 groups x 200 threads, 8x4 tiles, 20 b's each ----
  const int g = t >> 8;                 // b-quarter
  const int u = t & 255;
  const bool actA = (u < 200);
  const int rtA = u / 20;               // 0..9 (8-row j-tiles)
  const int ctA = u - rtA * 20;         // 0..19 (4-col a-tiles)
  const char* xbase = XHb + (2 * rtA) * 656 + g * 160;
  // swizzled write base: phys j-block = rtA ^ (ctA&3); a = ctA*4 + c
  char* mwp = MMb + g * 16640 + (ctA * 4) * 208 + ((rtA ^ (ctA & 3)) * 16);

  // persistent tgt registers: 4 a-cols x 20 b (10 b-pairs) = 10 uint4
  uint4 tr[10];
  #pragma unroll
  for (int cc = 0; cc < 10; ++cc)
    tr[cc] = *(const uint4*)(TTb + ctA * 656 + (g * 10 + cc) * 16);

  // persistent x-old registers for phase B
  float xo0[4], xo1[4];
  #pragma unroll
  for (int k = 0; k < 4; ++k) xo0[k] = xo1[k] = (float)(_Float16)(1.0f / 80.0f);

  for (int it = 0; it < MITERS; ++it) {
    // ---- Phase A: MM_g[a][j] = max_{b in quarter} x[j,b]*tgt[a,b] ----
    if (actA) {
      unsigned m[8][4];
      #pragma unroll
      for (int r = 0; r < 8; ++r)
        #pragma unroll
        for (int c = 0; c < 4; ++c) m[r][c] = 0u;
      #pragma unroll 2
      for (int cc = 0; cc < 10; ++cc) {
        const uint4 x0 = *(const uint4*)(xbase + cc * 16);
        const uint4 x1 = *(const uint4*)(xbase + 656 + cc * 16);
        const unsigned xr[8] = {x0.x, x0.y, x0.z, x0.w, x1.x, x1.y, x1.z, x1.w};
        const unsigned tc[4] = {tr[cc].x, tr[cc].y, tr[cc].z, tr[cc].w};
        #pragma unroll
        for (int r = 0; r < 8; ++r)
          #pragma unroll
          for (int c = 0; c < 4; ++c)
            m[r][c] = pk_max_f16(m[r][c], pk_mul_f16(xr[r], tc[c]));
      }
      #pragma unroll
      for (int c = 0; c < 4; ++c) {
        unsigned lo[8];
        #pragma unroll
        for (int r = 0; r < 8; ++r) {
          const unsigned v = m[r][c];
          lo[r] = pk_max_f16(v, (v >> 16) | (v << 16)) & 0xffffu;  // fold b-pair
        }
        const uint4 w = make_uint4(lo[0] | (lo[1] << 16), lo[2] | (lo[3] << 16),
                                   lo[4] | (lo[5] << 16), lo[6] | (lo[7] << 16));
        *(uint4*)(mwp + c * 208) = w;
      }
    }
    __syncthreads();

    // ---- Phase B: x_new = inv * (x*d + SRC @ max4(MM)) via MFMA ----
    const float* WIN = WSUM + ((it & 1) << 4);
    const float4 wa = *(const float4*)(WIN);
    const float4 wb = *(const float4*)(WIN + 4);
    const float4 wc = *(const float4*)(WIN + 8);
    const float4 wd = *(const float4*)(WIN + 12);
    const float tot = ((wa.x + wa.y) + (wa.z + wa.w)) +
                      ((wb.x + wb.y) + (wb.z + wb.w)) +
                      ((wc.x + wc.y) + (wc.z + wc.w)) +
                      ((wd.x + wd.y) + (wd.z + wd.w));
    const float inv = 1.0f / sqrtf(tot);

    float ss = 0.f;
    DO_TILE(i00, a00, af0, xo0);
    if (has2) DO_TILE(i01, a01, af1, xo1);

    #pragma unroll
    for (int off = 32; off > 0; off >>= 1) ss += __shfl_down(ss, off, 64);
    if (lane == 0) WSUM[(((it + 1) & 1) << 4) + wave] = ss;
    __syncthreads();
  }

  // ---- exact final normalization + output (out[1 + i*80 + a]) ----
  {
    const float* WF = WSUM + ((MITERS & 1) << 4);
    float tot = 0.f;
    #pragma unroll
    for (int w = 0; w < 16; ++w) tot += WF[w];
    const float finv = 1.0f / sqrtf(tot);
    for (int f = t; f < NN * NN; f += NTHREADS) {
      const int i = f / NN, a = f - (f / NN) * NN;
      out[1 + f] = (float)*(const _Float16*)(XHb + PB(i, a)) * finv;
    }
  }
}

extern "C" void kernel_launch(void* const* d_in, const int* in_sizes, int n_in,
                              void* d_out, int out_size, void* d_ws, size_t ws_size,
                              hipStream_t stream) {
  const float* recon = (const float*)d_in[0];
  const float* adj   = (const float*)d_in[1];
  float* out = (float*)d_out;
  (void)in_sizes; (void)n_in; (void)out_size; (void)d_ws; (void)ws_size;

  hipFuncSetAttribute(reinterpret_cast<const void*>(grf_kernel),
                      hipFuncAttributeMaxDynamicSharedMemorySize, LDS_BYTES);
  grf_kernel<<<1, NTHREADS, LDS_BYTES, stream>>>(recon, adj, out);
}

// Round 7
// 413.593 us; speedup vs baseline: 1.0745x; 1.0730x over previous
//
#include <hip/hip_runtime.h>
#include <math.h>

#define NN 80
#define MITERS 50
#define NTHREADS 1024

typedef _Float16 h8 __attribute__((ext_vector_type(8)));
typedef float f4 __attribute__((ext_vector_type(4)));

__device__ __forceinline__ unsigned pk_mul_f16(unsigned a, unsigned b) {
  unsigned d; asm("v_pk_mul_f16 %0, %1, %2" : "=v"(d) : "v"(a), "v"(b)); return d;
}
__device__ __forceinline__ unsigned pk_max_f16(unsigned a, unsigned b) {
  unsigned d; asm("v_pk_max_f16 %0, %1, %2" : "=v"(d) : "v"(a), "v"(b)); return d;
}
__device__ __forceinline__ h8 as_h8(uint4 u) {
  union { uint4 u; h8 h; } x; x.u = u; return x.h;
}

// ---- LDS byte offsets (16B-aligned) ----
#define OFF_XH    0
#define OFF_TT    13120
#define OFF_MM    26240          // 4 * 16640 = 66560
#define OFF_SRCH  92800
#define OFF_DLT   109440
#define OFF_FR    136320
#define OFF_FA    136640
#define OFF_RD    136960
#define OFF_AD    137280
#define OFF_WSUM  137600         // 2 x 16 f32 double-buffered
#define OFF_LSUM  137728         // 16 f32
#define LDS_BYTES 137792         // 134.6 KiB < 160 KiB

// paired fp16 byte index for element [r][k] of an 80x80 matrix
#define PB(r, k) ((((r) >> 2) * 656) + (((k) >> 1) * 16) + (((r) & 3) * 4) + (((k) & 1) * 2))

// MM swizzle: 16B j-block L of row a lives at phys block L ^ ((a>>2)&3).

// one MFMA C-tile of phase B: C[I0..+16][A0..+16] = SRC @ max4(MM0..MM3)
#define DO_TILE(I0, A0, AF, XO)                                               \
  {                                                                           \
    f4 acc = {0.f, 0.f, 0.f, 0.f};                                            \
    _Pragma("unroll")                                                         \
    for (int ks = 0; ks < 3; ++ks) {                                          \
      const int blk = (ks * 4 + gr) ^ mkey;                                   \
      const int mo = ((A0) + la) * 208 + blk * 16;                            \
      const uint4 b0 = *(const uint4*)(MMb + mo);                             \
      const uint4 b1 = *(const uint4*)(MMb + 16640 + mo);                     \
      const uint4 b2 = *(const uint4*)(MMb + 33280 + mo);                     \
      const uint4 b3 = *(const uint4*)(MMb + 49920 + mo);                     \
      uint4 bb;                                                               \
      bb.x = pk_max_f16(pk_max_f16(b0.x, b1.x), pk_max_f16(b2.x, b3.x));      \
      bb.y = pk_max_f16(pk_max_f16(b0.y, b1.y), pk_max_f16(b2.y, b3.y));      \
      bb.z = pk_max_f16(pk_max_f16(b0.z, b1.z), pk_max_f16(b2.z, b3.z));      \
      bb.w = pk_max_f16(pk_max_f16(b0.w, b1.w), pk_max_f16(b2.w, b3.w));      \
      acc = __builtin_amdgcn_mfma_f32_16x16x32_f16(as_h8(AF[ks]),             \
                                                   as_h8(bb), acc, 0, 0, 0);  \
    }                                                                         \
    const int col = (A0) + la;                                                \
    const int rb = (I0) + gr * 4;                                             \
    const float4 dl = *(const float4*)(DLTb + col * 336 + rb * 4);            \
    const float n0 = fmaf(XO[0], dl.x, acc[0]) * inv;                         \
    const float n1 = fmaf(XO[1], dl.y, acc[1]) * inv;                         \
    const float n2 = fmaf(XO[2], dl.z, acc[2]) * inv;                         \
    const float n3 = fmaf(XO[3], dl.w, acc[3]) * inv;                         \
    ss += n0 * n0 + n1 * n1 + n2 * n2 + n3 * n3;                              \
    XO[0] = n0; XO[1] = n1; XO[2] = n2; XO[3] = n3;                           \
    char* xa = XHb + (((I0) >> 2) + gr) * 656 + (col >> 1) * 16 + (col & 1) * 2; \
    *(_Float16*)(xa) = (_Float16)n0;                                          \
    *(_Float16*)(xa + 4) = (_Float16)n1;                                      \
    *(_Float16*)(xa + 8) = (_Float16)n2;                                      \
    *(_Float16*)(xa + 12) = (_Float16)n3;                                     \
  }

__global__ void __launch_bounds__(NTHREADS, 4)
grf_kernel(const float* __restrict__ recon, const float* __restrict__ adj,
           float* __restrict__ out) {
  extern __shared__ char ldsb[];
  char* XHb = ldsb + OFF_XH;
  char* TTb = ldsb + OFF_TT;
  char* MMb = ldsb + OFF_MM;
  char* SRCHb = ldsb + OFF_SRCH;
  char* DLTb = ldsb + OFF_DLT;
  float* FR = (float*)(ldsb + OFF_FR);
  float* FA = (float*)(ldsb + OFF_FA);
  float* RD = (float*)(ldsb + OFF_RD);
  float* AD = (float*)(ldsb + OFF_AD);
  float* WSUM = (float*)(ldsb + OFF_WSUM);
  float* LSUM = (float*)(ldsb + OFF_LSUM);

  const int t = threadIdx.x;
  const int wave = t >> 6, lane = t & 63;
  const int la = lane & 15, gr = lane >> 4;
  const int mkey = (la >> 2) & 3;  // MM read-side swizzle key

  // ---- row sums + diagonals ----
  if (t < 80) {
    float s = 0.f;
    for (int b = 0; b < NN; ++b) s += recon[t * NN + b];
    FR[t] = s;
    RD[t] = recon[t * NN + t];
  } else if (t < 160) {
    const int i = t - 80;
    float s = 0.f;
    for (int j = 0; j < NN; ++j) s += adj[i * NN + j];
    FA[i] = s;
    AD[i] = adj[i * NN + i];
  }
  if (t < 32) {
    const float q = (float)(_Float16)(1.0f / 80.0f);
    WSUM[t] = (t == 0) ? 6400.0f * q * q : 0.f;  // ||quantized x0||^2
  }
  __syncthreads();

  // ---- fill operand arrays + BCE loss over triu ----
  float lacc = 0.f;
  for (int f = t; f < NN * NN; f += NTHREADS) {
    const int r = f / NN, c = f - (f / NN) * NN;
    *(_Float16*)(XHb + PB(r, c)) = (_Float16)(1.0f / 80.0f);        // x0[i=r][a=c]
    const float tv = (r == c) ? 0.f : recon[r * NN + c] * RD[r] * RD[c];
    *(_Float16*)(TTb + PB(r, c)) = (_Float16)tv;                    // tgt[a=r][b=c]
    *(float*)(DLTb + (c * 84 + r) * 4) =
        AD[r] * RD[c] / (fabsf(FA[r] - FR[c]) + 1.f);               // DLT[a=c][i=r]
    const float sv = (r == c) ? 0.f : adj[r * NN + c] * AD[r] * AD[c];
    *(_Float16*)(SRCHb + (r * 104 + c) * 2) = (_Float16)sv;         // SRCH[i=r][j=c]
    if (c >= r) {
      const float tb = adj[f], p = recon[f];
      lacc -= tb * logf(p) + (1.f - tb) * logf(1.f - p);
    }
  }
  // zero pads: SRCH j in [80,104); all 4 MM buffers (16640 u32)
  for (int f = t; f < 1920; f += NTHREADS) {
    const int r = f / 24, j = 80 + (f - (f / 24) * 24);
    *(_Float16*)(SRCHb + (r * 104 + j) * 2) = (_Float16)0.f;
  }
  for (int f = t; f < 16640; f += NTHREADS) *(unsigned*)(MMb + f * 4) = 0u;

  #pragma unroll
  for (int off = 32; off > 0; off >>= 1) lacc += __shfl_down(lacc, off, 64);
  if (lane == 0) LSUM[wave] = lacc;
  __syncthreads();
  if (t == 0) {
    float s = 0.f;
    for (int w = 0; w < 16; ++w) s += LSUM[w];
    out[0] = s / 3240.f;  // 80*81/2
  }

  // ---- per-wave persistent SRC A-fragments ----
  const int i00 = (wave / 5) * 16, a00 = (wave % 5) * 16;
  const int tt1 = wave + 16;
  const bool has2 = tt1 < 25;
  const int i01 = has2 ? (tt1 / 5) * 16 : 0;
  const int a01 = has2 ? (tt1 % 5) * 16 : 0;
  uint4 af0[3], af1[3];
  af1[0] = af1[1] = af1[2] = make_uint4(0u, 0u, 0u, 0u);
  #pragma unroll
  for (int ks = 0; ks < 3; ++ks)
    af0[ks] = *(const uint4*)(SRCHb + (i00 + la) * 208 + ks * 64 + gr * 16);
  if (has2) {
    #pragma unroll
    for (int ks = 0; ks < 3; ++ks)
      af1[ks] = *(const uint4*)(SRCHb + (i01 + la) * 208 + ks * 64 + gr * 16);
  }

  // ---- phase-A mapping: 4 groups x 200 threads, 8x4 tiles, 20 b's each ----
  const int g = t >> 8;                 // b-quarter
  const int u = t & 255;
  const bool actA = (u < 200);
  const int rtA = u / 20;               // 0..9 (8-row j-tiles)
  const int ctA = u - rtA * 20;         // 0..19 (4-col a-tiles)
  const char* xbase = XHb + (2 * rtA) * 656 + g * 160;
  // swizzled write base: phys j-block = rtA ^ (ctA&3); a = ctA*4 + c
  char* mwp = MMb + g * 16640 + (ctA * 4) * 208 + ((rtA ^ (ctA & 3)) * 16);

  // persistent tgt registers: 4 a-cols x 20 b (10 b-pairs) = 10 uint4.
  // NOTE: every use of tr[] below is inside a FULLY unrolled loop (rule #20:
  // runtime indexing would demote the array to scratch).
  uint4 tr[10];
  #pragma unroll
  for (int cc = 0; cc < 10; ++cc)
    tr[cc] = *(const uint4*)(TTb + ctA * 656 + (g * 10 + cc) * 16);

  // persistent x-old registers for phase B
  float xo0[4], xo1[4];
  #pragma unroll
  for (int k = 0; k < 4; ++k) xo0[k] = xo1[k] = (float)(_Float16)(1.0f / 80.0f);

  for (int it = 0; it < MITERS; ++it) {
    // ---- Phase A: MM_g[a][j] = max_{b in quarter} x[j,b]*tgt[a,b] ----
    if (actA) {
      unsigned m[8][4];
      #pragma unroll
      for (int r = 0; r < 8; ++r)
        #pragma unroll
        for (int c = 0; c < 4; ++c) m[r][c] = 0u;
      #pragma unroll   // FULL unroll: keeps tr[cc] statically indexed (VGPRs)
      for (int cc = 0; cc < 10; ++cc) {
        const uint4 x0 = *(const uint4*)(xbase + cc * 16);
        const uint4 x1 = *(const uint4*)(xbase + 656 + cc * 16);
        const unsigned xr[8] = {x0.x, x0.y, x0.z, x0.w, x1.x, x1.y, x1.z, x1.w};
        const unsigned tc[4] = {tr[cc].x, tr[cc].y, tr[cc].z, tr[cc].w};
        #pragma unroll
        for (int r = 0; r < 8; ++r)
          #pragma unroll
          for (int c = 0; c < 4; ++c)
            m[r][c] = pk_max_f16(m[r][c], pk_mul_f16(xr[r], tc[c]));
      }
      #pragma unroll
      for (int c = 0; c < 4; ++c) {
        unsigned lo[8];
        #pragma unroll
        for (int r = 0; r < 8; ++r) {
          const unsigned v = m[r][c];
          lo[r] = pk_max_f16(v, (v >> 16) | (v << 16)) & 0xffffu;  // fold b-pair
        }
        const uint4 w = make_uint4(lo[0] | (lo[1] << 16), lo[2] | (lo[3] << 16),
                                   lo[4] | (lo[5] << 16), lo[6] | (lo[7] << 16));
        *(uint4*)(mwp + c * 208) = w;
      }
    }
    __syncthreads();

    // ---- Phase B: x_new = inv * (x*d + SRC @ max4(MM)) via MFMA ----
    const float* WIN = WSUM + ((it & 1) << 4);
    const float4 wa = *(const float4*)(WIN);
    const float4 wb = *(const float4*)(WIN + 4);
    const float4 wc = *(const float4*)(WIN + 8);
    const float4 wd = *(const float4*)(WIN + 12);
    const float tot = ((wa.x + wa.y) + (wa.z + wa.w)) +
                      ((wb.x + wb.y) + (wb.z + wb.w)) +
                      ((wc.x + wc.y) + (wc.z + wc.w)) +
                      ((wd.x + wd.y) + (wd.z + wd.w));
    const float inv = 1.0f / sqrtf(tot);

    float ss = 0.f;
    DO_TILE(i00, a00, af0, xo0);
    if (has2) DO_TILE(i01, a01, af1, xo1);

    #pragma unroll
    for (int off = 32; off > 0; off >>= 1) ss += __shfl_down(ss, off, 64);
    if (lane == 0) WSUM[(((it + 1) & 1) << 4) + wave] = ss;
    __syncthreads();
  }

  // ---- exact final normalization + output (out[1 + i*80 + a]) ----
  {
    const float* WF = WSUM + ((MITERS & 1) << 4);
    float tot = 0.f;
    #pragma unroll
    for (int w = 0; w < 16; ++w) tot += WF[w];
    const float finv = 1.0f / sqrtf(tot);
    for (int f = t; f < NN * NN; f += NTHREADS) {
      const int i = f / NN, a = f - (f / NN) * NN;
      out[1 + f] = (float)*(const _Float16*)(XHb + PB(i, a)) * finv;
    }
  }
}

extern "C" void kernel_launch(void* const* d_in, const int* in_sizes, int n_in,
                              void* d_out, int out_size, void* d_ws, size_t ws_size,
                              hipStream_t stream) {
  const float* recon = (const float*)d_in[0];
  const float* adj   = (const float*)d_in[1];
  float* out = (float*)d_out;
  (void)in_sizes; (void)n_in; (void)out_size; (void)d_ws; (void)ws_size;

  hipFuncSetAttribute(reinterpret_cast<const void*>(grf_kernel),
                      hipFuncAttributeMaxDynamicSharedMemorySize, LDS_BYTES);
  grf_kernel<<<1, NTHREADS, LDS_BYTES, stream>>>(recon, adj, out);
}

// Round 8
// 404.514 us; speedup vs baseline: 1.0986x; 1.0224x over previous
//
#include <hip/hip_runtime.h>
#include <math.h>

#define NN 80
#define MITERS 50
#define NTHREADS 1024

typedef _Float16 h8 __attribute__((ext_vector_type(8)));
typedef float f4 __attribute__((ext_vector_type(4)));

__device__ __forceinline__ unsigned pk_mul_f16(unsigned a, unsigned b) {
  unsigned d; asm("v_pk_mul_f16 %0, %1, %2" : "=v"(d) : "v"(a), "v"(b)); return d;
}
__device__ __forceinline__ unsigned pk_max_f16(unsigned a, unsigned b) {
  unsigned d; asm("v_pk_max_f16 %0, %1, %2" : "=v"(d) : "v"(a), "v"(b)); return d;
}
__device__ __forceinline__ h8 as_h8(uint4 u) {
  union { uint4 u; h8 h; } x; x.u = u; return x.h;
}

// ---- LDS byte offsets (16B-aligned) ----
#define OFF_XH    0
#define OFF_TT    13120
#define OFF_MM    26240          // 4 * 16640 = 66560
#define OFF_SRCH  92800
#define OFF_DLT   109440
#define OFF_FR    136320
#define OFF_FA    136640
#define OFF_RD    136960
#define OFF_AD    137280
#define OFF_WSUM  137600         // 2 x 16 f32 double-buffered
#define OFF_LSUM  137728         // 16 f32
#define LDS_BYTES 137792         // 134.6 KiB < 160 KiB

// paired fp16 byte index for element [r][k] of an 80x80 matrix
#define PB(r, k) ((((r) >> 2) * 656) + (((k) >> 1) * 16) + (((r) & 3) * 4) + (((k) & 1) * 2))

// MM swizzle: 16B j-block L of row a lives at phys block L ^ ((a>>2)&3).

// one MFMA C-tile of phase B: C[I0..+16][A0..+16] = SRC @ max4(MM0..MM3)
// A-fragments re-read from static SRCH each call (saves 24 persistent VGPRs).
#define DO_TILE(I0, A0, XO)                                                   \
  {                                                                           \
    f4 acc = {0.f, 0.f, 0.f, 0.f};                                            \
    _Pragma("unroll")                                                         \
    for (int ks = 0; ks < 3; ++ks) {                                          \
      const uint4 afr =                                                       \
          *(const uint4*)(SRCHb + ((I0) + la) * 208 + ks * 64 + gr * 16);     \
      const int blk = (ks * 4 + gr) ^ mkey;                                   \
      const int mo = ((A0) + la) * 208 + blk * 16;                            \
      const uint4 b0 = *(const uint4*)(MMb + mo);                             \
      const uint4 b1 = *(const uint4*)(MMb + 16640 + mo);                     \
      const uint4 b2 = *(const uint4*)(MMb + 33280 + mo);                     \
      const uint4 b3 = *(const uint4*)(MMb + 49920 + mo);                     \
      uint4 bb;                                                               \
      bb.x = pk_max_f16(pk_max_f16(b0.x, b1.x), pk_max_f16(b2.x, b3.x));      \
      bb.y = pk_max_f16(pk_max_f16(b0.y, b1.y), pk_max_f16(b2.y, b3.y));      \
      bb.z = pk_max_f16(pk_max_f16(b0.z, b1.z), pk_max_f16(b2.z, b3.z));      \
      bb.w = pk_max_f16(pk_max_f16(b0.w, b1.w), pk_max_f16(b2.w, b3.w));      \
      acc = __builtin_amdgcn_mfma_f32_16x16x32_f16(as_h8(afr),                \
                                                   as_h8(bb), acc, 0, 0, 0);  \
    }                                                                         \
    const int col = (A0) + la;                                                \
    const int rb = (I0) + gr * 4;                                             \
    const float4 dl = *(const float4*)(DLTb + col * 336 + rb * 4);            \
    const float n0 = fmaf(XO[0], dl.x, acc[0]) * inv;                         \
    const float n1 = fmaf(XO[1], dl.y, acc[1]) * inv;                         \
    const float n2 = fmaf(XO[2], dl.z, acc[2]) * inv;                         \
    const float n3 = fmaf(XO[3], dl.w, acc[3]) * inv;                         \
    ss += n0 * n0 + n1 * n1 + n2 * n2 + n3 * n3;                              \
    XO[0] = n0; XO[1] = n1; XO[2] = n2; XO[3] = n3;                           \
    char* xa = XHb + (((I0) >> 2) + gr) * 656 + (col >> 1) * 16 + (col & 1) * 2; \
    *(_Float16*)(xa) = (_Float16)n0;                                          \
    *(_Float16*)(xa + 4) = (_Float16)n1;                                      \
    *(_Float16*)(xa + 8) = (_Float16)n2;                                      \
    *(_Float16*)(xa + 12) = (_Float16)n3;                                     \
  }

__global__ void __launch_bounds__(NTHREADS, 4)
__attribute__((amdgpu_waves_per_eu(4, 4)))   // pin allocator target: 4 waves/EU -> 128-VGPR budget
grf_kernel(const float* __restrict__ recon, const float* __restrict__ adj,
           float* __restrict__ out) {
  extern __shared__ char ldsb[];
  char* XHb = ldsb + OFF_XH;
  char* TTb = ldsb + OFF_TT;
  char* MMb = ldsb + OFF_MM;
  char* SRCHb = ldsb + OFF_SRCH;
  char* DLTb = ldsb + OFF_DLT;
  float* FR = (float*)(ldsb + OFF_FR);
  float* FA = (float*)(ldsb + OFF_FA);
  float* RD = (float*)(ldsb + OFF_RD);
  float* AD = (float*)(ldsb + OFF_AD);
  float* WSUM = (float*)(ldsb + OFF_WSUM);
  float* LSUM = (float*)(ldsb + OFF_LSUM);

  const int t = threadIdx.x;
  const int wave = t >> 6, lane = t & 63;
  const int la = lane & 15, gr = lane >> 4;
  const int mkey = (la >> 2) & 3;  // MM read-side swizzle key

  // ---- row sums + diagonals ----
  if (t < 80) {
    float s = 0.f;
    for (int b = 0; b < NN; ++b) s += recon[t * NN + b];
    FR[t] = s;
    RD[t] = recon[t * NN + t];
  } else if (t < 160) {
    const int i = t - 80;
    float s = 0.f;
    for (int j = 0; j < NN; ++j) s += adj[i * NN + j];
    FA[i] = s;
    AD[i] = adj[i * NN + i];
  }
  if (t < 32) {
    const float q = (float)(_Float16)(1.0f / 80.0f);
    WSUM[t] = (t == 0) ? 6400.0f * q * q : 0.f;  // ||quantized x0||^2
  }
  __syncthreads();

  // ---- fill operand arrays + BCE loss over triu ----
  float lacc = 0.f;
  for (int f = t; f < NN * NN; f += NTHREADS) {
    const int r = f / NN, c = f - (f / NN) * NN;
    *(_Float16*)(XHb + PB(r, c)) = (_Float16)(1.0f / 80.0f);        // x0[i=r][a=c]
    const float tv = (r == c) ? 0.f : recon[r * NN + c] * RD[r] * RD[c];
    *(_Float16*)(TTb + PB(r, c)) = (_Float16)tv;                    // tgt[a=r][b=c]
    *(float*)(DLTb + (c * 84 + r) * 4) =
        AD[r] * RD[c] / (fabsf(FA[r] - FR[c]) + 1.f);               // DLT[a=c][i=r]
    const float sv = (r == c) ? 0.f : adj[r * NN + c] * AD[r] * AD[c];
    *(_Float16*)(SRCHb + (r * 104 + c) * 2) = (_Float16)sv;         // SRCH[i=r][j=c]
    if (c >= r) {
      const float tb = adj[f], p = recon[f];
      lacc -= tb * logf(p) + (1.f - tb) * logf(1.f - p);
    }
  }
  // zero pads: SRCH j in [80,104); all 4 MM buffers (16640 u32)
  for (int f = t; f < 1920; f += NTHREADS) {
    const int r = f / 24, j = 80 + (f - (f / 24) * 24);
    *(_Float16*)(SRCHb + (r * 104 + j) * 2) = (_Float16)0.f;
  }
  for (int f = t; f < 16640; f += NTHREADS) *(unsigned*)(MMb + f * 4) = 0u;

  #pragma unroll
  for (int off = 32; off > 0; off >>= 1) lacc += __shfl_down(lacc, off, 64);
  if (lane == 0) LSUM[wave] = lacc;
  __syncthreads();
  if (t == 0) {
    float s = 0.f;
    for (int w = 0; w < 16; ++w) s += LSUM[w];
    out[0] = s / 3240.f;  // 80*81/2
  }

  // ---- per-wave MFMA tile assignments (fragments re-read per iter) ----
  const int i00 = (wave / 5) * 16, a00 = (wave % 5) * 16;
  const int tt1 = wave + 16;
  const bool has2 = tt1 < 25;
  const int i01 = has2 ? (tt1 / 5) * 16 : 0;
  const int a01 = has2 ? (tt1 % 5) * 16 : 0;

  // ---- phase-A mapping: 4 groups x 200 threads, 8x4 tiles, 20 b's each ----
  const int g = t >> 8;                 // b-quarter
  const int u = t & 255;
  const bool actA = (u < 200);
  const int rtA = u / 20;               // 0..9 (8-row j-tiles)
  const int ctA = u - rtA * 20;         // 0..19 (4-col a-tiles)
  const char* xbase = XHb + (2 * rtA) * 656 + g * 160;
  // swizzled write base: phys j-block = rtA ^ (ctA&3); a = ctA*4 + c
  char* mwp = MMb + g * 16640 + (ctA * 4) * 208 + ((rtA ^ (ctA & 3)) * 16);

  // persistent tgt registers: 4 a-cols x 20 b (10 b-pairs) = 10 uint4.
  // Every use is inside FULLY unrolled loops (rule #20).
  uint4 tr[10];
  #pragma unroll
  for (int cc = 0; cc < 10; ++cc)
    tr[cc] = *(const uint4*)(TTb + ctA * 656 + (g * 10 + cc) * 16);

  // persistent x-old registers for phase B
  float xo0[4], xo1[4];
  #pragma unroll
  for (int k = 0; k < 4; ++k) xo0[k] = xo1[k] = (float)(_Float16)(1.0f / 80.0f);

  for (int it = 0; it < MITERS; ++it) {
    // ---- Phase A: MM_g[a][j] = max_{b in quarter} x[j,b]*tgt[a,b] ----
    if (actA) {
      unsigned m[8][4];
      #pragma unroll
      for (int r = 0; r < 8; ++r)
        #pragma unroll
        for (int c = 0; c < 4; ++c) m[r][c] = 0u;
      #pragma unroll   // FULL unroll: keeps tr[cc] statically indexed (VGPRs)
      for (int cc = 0; cc < 10; ++cc) {
        const uint4 x0 = *(const uint4*)(xbase + cc * 16);
        const uint4 x1 = *(const uint4*)(xbase + 656 + cc * 16);
        const unsigned xr[8] = {x0.x, x0.y, x0.z, x0.w, x1.x, x1.y, x1.z, x1.w};
        const unsigned tc[4] = {tr[cc].x, tr[cc].y, tr[cc].z, tr[cc].w};
        #pragma unroll
        for (int r = 0; r < 8; ++r)
          #pragma unroll
          for (int c = 0; c < 4; ++c)
            m[r][c] = pk_max_f16(m[r][c], pk_mul_f16(xr[r], tc[c]));
      }
      #pragma unroll
      for (int c = 0; c < 4; ++c) {
        unsigned lo[8];
        #pragma unroll
        for (int r = 0; r < 8; ++r) {
          const unsigned v = m[r][c];
          lo[r] = pk_max_f16(v, (v >> 16) | (v << 16)) & 0xffffu;  // fold b-pair
        }
        const uint4 w = make_uint4(lo[0] | (lo[1] << 16), lo[2] | (lo[3] << 16),
                                   lo[4] | (lo[5] << 16), lo[6] | (lo[7] << 16));
        *(uint4*)(mwp + c * 208) = w;
      }
    }
    __syncthreads();

    // ---- Phase B: x_new = inv * (x*d + SRC @ max4(MM)) via MFMA ----
    const float* WIN = WSUM + ((it & 1) << 4);
    const float4 wa = *(const float4*)(WIN);
    const float4 wb = *(const float4*)(WIN + 4);
    const float4 wc = *(const float4*)(WIN + 8);
    const float4 wd = *(const float4*)(WIN + 12);
    const float tot = ((wa.x + wa.y) + (wa.z + wa.w)) +
                      ((wb.x + wb.y) + (wb.z + wb.w)) +
                      ((wc.x + wc.y) + (wc.z + wc.w)) +
                      ((wd.x + wd.y) + (wd.z + wd.w));
    const float inv = 1.0f / sqrtf(tot);

    float ss = 0.f;
    DO_TILE(i00, a00, xo0);
    if (has2) DO_TILE(i01, a01, xo1);

    #pragma unroll
    for (int off = 32; off > 0; off >>= 1) ss += __shfl_down(ss, off, 64);
    if (lane == 0) WSUM[(((it + 1) & 1) << 4) + wave] = ss;
    __syncthreads();
  }

  // ---- exact final normalization + output (out[1 + i*80 + a]) ----
  {
    const float* WF = WSUM + ((MITERS & 1) << 4);
    float tot = 0.f;
    #pragma unroll
    for (int w = 0; w < 16; ++w) tot += WF[w];
    const float finv = 1.0f / sqrtf(tot);
    for (int f = t; f < NN * NN; f += NTHREADS) {
      const int i = f / NN, a = f - (f / NN) * NN;
      out[1 + f] = (float)*(const _Float16*)(XHb + PB(i, a)) * finv;
    }
  }
}

extern "C" void kernel_launch(void* const* d_in, const int* in_sizes, int n_in,
                              void* d_out, int out_size, void* d_ws, size_t ws_size,
                              hipStream_t stream) {
  const float* recon = (const float*)d_in[0];
  const float* adj   = (const float*)d_in[1];
  float* out = (float*)d_out;
  (void)in_sizes; (void)n_in; (void)out_size; (void)d_ws; (void)ws_size;

  hipFuncSetAttribute(reinterpret_cast<const void*>(grf_kernel),
                      hipFuncAttributeMaxDynamicSharedMemorySize, LDS_BYTES);
  grf_kernel<<<1, NTHREADS, LDS_BYTES, stream>>>(recon, adj, out);
}

// Round 9
// 368.420 us; speedup vs baseline: 1.2062x; 1.0980x over previous
//
#include <hip/hip_runtime.h>
#include <math.h>

#define NN 80
#define MITERS 50
#define NTHREADS 1024

typedef _Float16 h8 __attribute__((ext_vector_type(8)));
typedef float f4 __attribute__((ext_vector_type(4)));

__device__ __forceinline__ unsigned pk_mul_f16(unsigned a, unsigned b) {
  unsigned d; asm("v_pk_mul_f16 %0, %1, %2" : "=v"(d) : "v"(a), "v"(b)); return d;
}
__device__ __forceinline__ unsigned pk_max_f16(unsigned a, unsigned b) {
  unsigned d; asm("v_pk_max_f16 %0, %1, %2" : "=v"(d) : "v"(a), "v"(b)); return d;
}
__device__ __forceinline__ h8 as_h8(uint4 u) {
  union { uint4 u; h8 h; } x; x.u = u; return x.h;
}

// ---- LDS byte offsets (16B-aligned) ----
#define OFF_XH    0
#define OFF_TT    13120
#define OFF_MM    26240          // 2 * 16640 = 33280
#define OFF_SRCH  59520
#define OFF_DLT   76160
#define OFF_FR    103040
#define OFF_FA    103360
#define OFF_RD    103680
#define OFF_AD    104000
#define OFF_WSUM  104320         // 2 x 16 f32 double-buffered
#define OFF_LSUM  104448         // 16 f32
#define LDS_BYTES 104512         // 102.1 KiB < 160 KiB

// paired fp16 byte index for element [r][k] of an 80x80 matrix
#define PB(r, k) ((((r) >> 2) * 656) + (((k) >> 1) * 16) + (((r) & 3) * 4) + (((k) & 1) * 2))

// MM swizzle: 16B j-block L of row a lives at phys block L ^ ((a>>2)&3).
// Writer and reader both key on the same a-bits, so it's a per-row bijection;
// phys blocks 10^key..  are never written by row a's writers (rt>>1 <= 9), and
// the full-buffer zero-init covers them -> pad reads stay 0.

// one MFMA C-tile of phase B: C[I0..+16][A0..+16] = SRC @ max(MM0,MM1)
// A-fragments re-read from static SRCH each call (keeps live regs < 64).
#define DO_TILE(I0, A0, XO)                                                   \
  {                                                                           \
    f4 acc = {0.f, 0.f, 0.f, 0.f};                                            \
    _Pragma("unroll")                                                         \
    for (int ks = 0; ks < 3; ++ks) {                                          \
      const uint4 afr =                                                       \
          *(const uint4*)(SRCHb + ((I0) + la) * 208 + ks * 64 + gr * 16);     \
      const int blk = (ks * 4 + gr) ^ mkey;                                   \
      const int mo = ((A0) + la) * 208 + blk * 16;                            \
      const uint4 b0 = *(const uint4*)(MMb + mo);                             \
      const uint4 b1 = *(const uint4*)(MMb + 16640 + mo);                     \
      uint4 bb;                                                               \
      bb.x = pk_max_f16(b0.x, b1.x);                                          \
      bb.y = pk_max_f16(b0.y, b1.y);                                          \
      bb.z = pk_max_f16(b0.z, b1.z);                                          \
      bb.w = pk_max_f16(b0.w, b1.w);                                          \
      acc = __builtin_amdgcn_mfma_f32_16x16x32_f16(as_h8(afr),                \
                                                   as_h8(bb), acc, 0, 0, 0);  \
    }                                                                         \
    const int col = (A0) + la;                                                \
    const int rb = (I0) + gr * 4;                                             \
    const float4 dl = *(const float4*)(DLTb + col * 336 + rb * 4);            \
    const float n0 = fmaf(XO[0], dl.x, acc[0]) * inv;                         \
    const float n1 = fmaf(XO[1], dl.y, acc[1]) * inv;                         \
    const float n2 = fmaf(XO[2], dl.z, acc[2]) * inv;                         \
    const float n3 = fmaf(XO[3], dl.w, acc[3]) * inv;                         \
    ss += n0 * n0 + n1 * n1 + n2 * n2 + n3 * n3;                              \
    XO[0] = n0; XO[1] = n1; XO[2] = n2; XO[3] = n3;                           \
    char* xa = XHb + (((I0) >> 2) + gr) * 656 + (col >> 1) * 16 + (col & 1) * 2; \
    *(_Float16*)(xa) = (_Float16)n0;                                          \
    *(_Float16*)(xa + 4) = (_Float16)n1;                                      \
    *(_Float16*)(xa + 8) = (_Float16)n2;                                      \
    *(_Float16*)(xa + 12) = (_Float16)n3;                                     \
  }

__global__ void __launch_bounds__(NTHREADS, 4)
grf_kernel(const float* __restrict__ recon, const float* __restrict__ adj,
           float* __restrict__ out) {
  extern __shared__ char ldsb[];
  char* XHb = ldsb + OFF_XH;
  char* TTb = ldsb + OFF_TT;
  char* MMb = ldsb + OFF_MM;
  char* SRCHb = ldsb + OFF_SRCH;
  char* DLTb = ldsb + OFF_DLT;
  float* FR = (float*)(ldsb + OFF_FR);
  float* FA = (float*)(ldsb + OFF_FA);
  float* RD = (float*)(ldsb + OFF_RD);
  float* AD = (float*)(ldsb + OFF_AD);
  float* WSUM = (float*)(ldsb + OFF_WSUM);
  float* LSUM = (float*)(ldsb + OFF_LSUM);

  const int t = threadIdx.x;
  const int wave = t >> 6, lane = t & 63;
  const int la = lane & 15, gr = lane >> 4;
  const int mkey = (la >> 2) & 3;  // MM read-side swizzle key

  // ---- row sums + diagonals ----
  if (t < 80) {
    float s = 0.f;
    for (int b = 0; b < NN; ++b) s += recon[t * NN + b];
    FR[t] = s;
    RD[t] = recon[t * NN + t];
  } else if (t < 160) {
    const int i = t - 80;
    float s = 0.f;
    for (int j = 0; j < NN; ++j) s += adj[i * NN + j];
    FA[i] = s;
    AD[i] = adj[i * NN + i];
  }
  if (t < 32) {
    const float q = (float)(_Float16)(1.0f / 80.0f);
    WSUM[t] = (t == 0) ? 6400.0f * q * q : 0.f;  // ||quantized x0||^2
  }
  __syncthreads();

  // ---- fill operand arrays + BCE loss over triu ----
  float lacc = 0.f;
  for (int f = t; f < NN * NN; f += NTHREADS) {
    const int r = f / NN, c = f - (f / NN) * NN;
    *(_Float16*)(XHb + PB(r, c)) = (_Float16)(1.0f / 80.0f);        // x0[i=r][a=c]
    const float tv = (r == c) ? 0.f : recon[r * NN + c] * RD[r] * RD[c];
    *(_Float16*)(TTb + PB(r, c)) = (_Float16)tv;                    // tgt[a=r][b=c]
    *(float*)(DLTb + (c * 84 + r) * 4) =
        AD[r] * RD[c] / (fabsf(FA[r] - FR[c]) + 1.f);               // DLT[a=c][i=r]
    const float sv = (r == c) ? 0.f : adj[r * NN + c] * AD[r] * AD[c];
    *(_Float16*)(SRCHb + (r * 104 + c) * 2) = (_Float16)sv;         // SRCH[i=r][j=c]
    if (c >= r) {
      const float tb = adj[f], p = recon[f];
      lacc -= tb * logf(p) + (1.f - tb) * logf(1.f - p);
    }
  }
  // zero pads: SRCH j in [80,104); both MM buffers (8320 u32)
  for (int f = t; f < 1920; f += NTHREADS) {
    const int r = f / 24, j = 80 + (f - (f / 24) * 24);
    *(_Float16*)(SRCHb + (r * 104 + j) * 2) = (_Float16)0.f;
  }
  for (int f = t; f < 8320; f += NTHREADS) *(unsigned*)(MMb + f * 4) = 0u;

  #pragma unroll
  for (int off = 32; off > 0; off >>= 1) lacc += __shfl_down(lacc, off, 64);
  if (lane == 0) LSUM[wave] = lacc;
  __syncthreads();
  if (t == 0) {
    float s = 0.f;
    for (int w = 0; w < 16; ++w) s += LSUM[w];
    out[0] = s / 3240.f;  // 80*81/2
  }

  // ---- per-wave MFMA tile assignments (fragments re-read per iter) ----
  const int i00 = (wave / 5) * 16, a00 = (wave % 5) * 16;
  const int tt1 = wave + 16;
  const bool has2 = tt1 < 25;
  const int i01 = has2 ? (tt1 / 5) * 16 : 0;
  const int a01 = has2 ? (tt1 % 5) * 16 : 0;

  // ---- phase-A mapping: 2 halves x 400 threads, 4x4 tiles, 40 b's each ----
  const int g = t >> 9;                 // b-half
  const int u = t & 511;
  const bool actA = (u < 400);
  const int rt = u / 20;                // 0..19 (4-row j-quads)
  const int ct = u - rt * 20;           // 0..19 (4-col a-tiles)
  const char* xAp = XHb + rt * 656 + g * 320;   // x[j-quad rt][b-half g]
  const char* tAp = TTb + ct * 656 + g * 320;   // tgt[a-quad ct][b-half g]
  // swizzled write base: 16B block (rt>>1)^(ct&3), 8B sub-block rt&1
  char* mwp = MMb + g * 16640 + (ct * 4) * 208 +
              (((rt >> 1) ^ (ct & 3)) * 16) + ((rt & 1) * 8);

  // persistent x-old registers for phase B (the only persistent state)
  float xo0[4], xo1[4];
  #pragma unroll
  for (int k = 0; k < 4; ++k) xo0[k] = xo1[k] = (float)(_Float16)(1.0f / 80.0f);

  for (int it = 0; it < MITERS; ++it) {
    // ---- Phase A: MM_g[a][j] = max_{b in half} x[j,b]*tgt[a,b] ----
    if (actA) {
      unsigned m[4][4];
      #pragma unroll
      for (int r = 0; r < 4; ++r)
        #pragma unroll
        for (int c = 0; c < 4; ++c) m[r][c] = 0u;
      #pragma unroll 4
      for (int cc = 0; cc < 20; ++cc) {   // 20 b-pairs in this half
        const uint4 xq = *(const uint4*)(xAp + cc * 16);
        const uint4 tq = *(const uint4*)(tAp + cc * 16);
        const unsigned xr[4] = {xq.x, xq.y, xq.z, xq.w};
        const unsigned tc[4] = {tq.x, tq.y, tq.z, tq.w};
        #pragma unroll
        for (int r = 0; r < 4; ++r)
          #pragma unroll
          for (int c = 0; c < 4; ++c)
            m[r][c] = pk_max_f16(m[r][c], pk_mul_f16(xr[r], tc[c]));
      }
      #pragma unroll
      for (int c = 0; c < 4; ++c) {
        unsigned lo[4];
        #pragma unroll
        for (int r = 0; r < 4; ++r) {
          const unsigned v = m[r][c];
          lo[r] = pk_max_f16(v, (v >> 16) | (v << 16)) & 0xffffu;  // fold b-pair
        }
        const uint2 w = make_uint2(lo[0] | (lo[1] << 16), lo[2] | (lo[3] << 16));
        *(uint2*)(mwp + c * 208) = w;   // rows rt*4..rt*4+3 of col ct*4+c
      }
    }
    __syncthreads();

    // ---- Phase B: x_new = inv * (x*d + SRC @ max(MM0,MM1)) via MFMA ----
    const float* WIN = WSUM + ((it & 1) << 4);
    const float4 wa = *(const float4*)(WIN);
    const float4 wb = *(const float4*)(WIN + 4);
    const float4 wc = *(const float4*)(WIN + 8);
    const float4 wd = *(const float4*)(WIN + 12);
    const float tot = ((wa.x + wa.y) + (wa.z + wa.w)) +
                      ((wb.x + wb.y) + (wb.z + wb.w)) +
                      ((wc.x + wc.y) + (wc.z + wc.w)) +
                      ((wd.x + wd.y) + (wd.z + wd.w));
    const float inv = 1.0f / sqrtf(tot);

    float ss = 0.f;
    DO_TILE(i00, a00, xo0);
    if (has2) DO_TILE(i01, a01, xo1);

    #pragma unroll
    for (int off = 32; off > 0; off >>= 1) ss += __shfl_down(ss, off, 64);
    if (lane == 0) WSUM[(((it + 1) & 1) << 4) + wave] = ss;
    __syncthreads();
  }

  // ---- exact final normalization + output (out[1 + i*80 + a]) ----
  {
    const float* WF = WSUM + ((MITERS & 1) << 4);
    float tot = 0.f;
    #pragma unroll
    for (int w = 0; w < 16; ++w) tot += WF[w];
    const float finv = 1.0f / sqrtf(tot);
    for (int f = t; f < NN * NN; f += NTHREADS) {
      const int i = f / NN, a = f - (f / NN) * NN;
      out[1 + f] = (float)*(const _Float16*)(XHb + PB(i, a)) * finv;
    }
  }
}

extern "C" void kernel_launch(void* const* d_in, const int* in_sizes, int n_in,
                              void* d_out, int out_size, void* d_ws, size_t ws_size,
                              hipStream_t stream) {
  const float* recon = (const float*)d_in[0];
  const float* adj   = (const float*)d_in[1];
  float* out = (float*)d_out;
  (void)in_sizes; (void)n_in; (void)out_size; (void)d_ws; (void)ws_size;

  hipFuncSetAttribute(reinterpret_cast<const void*>(grf_kernel),
                      hipFuncAttributeMaxDynamicSharedMemorySize, LDS_BYTES);
  grf_kernel<<<1, NTHREADS, LDS_BYTES, stream>>>(recon, adj, out);
}

// Round 11
// 350.566 us; speedup vs baseline: 1.2677x; 1.0509x over previous
//
#include <hip/hip_runtime.h>
#include <math.h>

#define NN 80
#define MITERS 50
#define NTHREADS 1024

typedef _Float16 h8 __attribute__((ext_vector_type(8)));
typedef _Float16 h2 __attribute__((ext_vector_type(2)));
typedef float f4 __attribute__((ext_vector_type(4)));

__device__ __forceinline__ unsigned pk_mul_f16(unsigned a, unsigned b) {
  unsigned d; asm("v_pk_mul_f16 %0, %1, %2" : "=v"(d) : "v"(a), "v"(b)); return d;
}
__device__ __forceinline__ unsigned pk_max_f16(unsigned a, unsigned b) {
  unsigned d; asm("v_pk_max_f16 %0, %1, %2" : "=v"(d) : "v"(a), "v"(b)); return d;
}
__device__ __forceinline__ h8 as_h8(uint4 u) {
  union { uint4 u; h8 h; } x; x.u = u; return x.h;
}
// wave64 sum via DPP (VALU-only, frees the LDS pipe); ctrl must be constexpr
template <int CTRL>
__device__ __forceinline__ float dpp_add(float x) {
  int yi = __builtin_amdgcn_update_dpp(0, __builtin_bit_cast(int, x),
                                       CTRL, 0xf, 0xf, true);
  return x + __builtin_bit_cast(float, yi);
}

// ---- LDS byte offsets (16B-aligned) ----
// XH : fp16 [80][88]  row-major x[i][a], stride 176B
// TT : fp16 [80][96]  tgt[a][b], stride 192B, 16B-chunk swizzle ^((a>>2)&3)
// MM : 2 bufs fp16 [80 a][104 j], stride 208B, j-block swizzle ^((a>>2)&3)
// SRCH: fp16 [80 i][104 j] (0/1), stride 208B, zero pad j>=80
// DL : f32 [80 i][84 a], stride 336B
#define OFF_XH    0
#define OFF_TT    14080
#define OFF_MM    29440
#define OFF_SRCH  62720
#define OFF_DL    79360
#define OFF_FR    106240
#define OFF_FA    106560
#define OFF_RD    106880
#define OFF_AD    107200
#define OFF_WSUM  107520    // 2 x 16 f32, double-buffered
#define OFF_TOT   107648    // 2 f32 (pre-summed norm)
#define OFF_LSUM  107664    // 16 f32
#define LDS_BYTES 107728    // 105.2 KiB < 160 KiB

// one MFMA C-tile of phase B, TRANSPOSED-C form:
// acc = MM(rows a) x SRC(cols i)  ->  lane la = i-col, rows gr*4+q = a
#define DO_TILE(I0, A0, XO)                                                   \
  {                                                                           \
    f4 acc = {0.f, 0.f, 0.f, 0.f};                                            \
    _Pragma("unroll")                                                         \
    for (int ks = 0; ks < 3; ++ks) {                                          \
      const int mo = ((A0) + la) * 208 + (((ks * 4 + gr) ^ mkey) * 16);       \
      const uint4 b0 = *(const uint4*)(MMb + mo);                             \
      const uint4 b1 = *(const uint4*)(MMb + 16640 + mo);                     \
      uint4 bb;                                                               \
      bb.x = pk_max_f16(b0.x, b1.x);                                          \
      bb.y = pk_max_f16(b0.y, b1.y);                                          \
      bb.z = pk_max_f16(b0.z, b1.z);                                          \
      bb.w = pk_max_f16(b0.w, b1.w);                                          \
      const uint4 afr =                                                       \
          *(const uint4*)(SRCHb + ((I0) + la) * 208 + ks * 64 + gr * 16);     \
      acc = __builtin_amdgcn_mfma_f32_16x16x32_f16(as_h8(bb),                 \
                                                   as_h8(afr), acc, 0, 0, 0); \
    }                                                                         \
    const int iN = (I0) + la;                                                 \
    const int ab = (A0) + gr * 4;                                             \
    const float4 dl = *(const float4*)(DLb + iN * 336 + ab * 4);              \
    const float n0 = fmaf(XO[0], dl.x, acc[0]) * inv;                         \
    const float n1 = fmaf(XO[1], dl.y, acc[1]) * inv;                         \
    const float n2 = fmaf(XO[2], dl.z, acc[2]) * inv;                         \
    const float n3 = fmaf(XO[3], dl.w, acc[3]) * inv;                         \
    ss += n0 * n0 + n1 * n1 + n2 * n2 + n3 * n3;                              \
    XO[0] = n0; XO[1] = n1; XO[2] = n2; XO[3] = n3;                           \
    const unsigned ulo = __builtin_bit_cast(                                  \
        unsigned, __builtin_amdgcn_cvt_pkrtz(n0, n1));                        \
    const unsigned uhi = __builtin_bit_cast(                                  \
        unsigned, __builtin_amdgcn_cvt_pkrtz(n2, n3));                        \
    *(uint2*)(XHb + iN * 176 + ab * 2) = make_uint2(ulo, uhi);                \
  }

__global__ void __launch_bounds__(NTHREADS, 4)
grf_kernel(const float* __restrict__ recon, const float* __restrict__ adj,
           float* __restrict__ out) {
  extern __shared__ char ldsb[];
  char* XHb = ldsb + OFF_XH;
  char* TTb = ldsb + OFF_TT;
  char* MMb = ldsb + OFF_MM;
  char* SRCHb = ldsb + OFF_SRCH;
  char* DLb = ldsb + OFF_DL;
  float* FR = (float*)(ldsb + OFF_FR);
  float* FA = (float*)(ldsb + OFF_FA);
  float* RD = (float*)(ldsb + OFF_RD);
  float* AD = (float*)(ldsb + OFF_AD);
  float* WSUM = (float*)(ldsb + OFF_WSUM);
  float* TOT = (float*)(ldsb + OFF_TOT);
  float* LSUM = (float*)(ldsb + OFF_LSUM);

  const int t = threadIdx.x;
  const int wave = t >> 6, lane = t & 63;
  const int la = lane & 15, gr = lane >> 4;
  const int mkey = (la >> 2) & 3;  // MM read-side swizzle key

  // ---- row sums + diagonals ----
  if (t < 80) {
    float s = 0.f;
    for (int b = 0; b < NN; ++b) s += recon[t * NN + b];
    FR[t] = s;
    RD[t] = recon[t * NN + t];
  } else if (t < 160) {
    const int i = t - 80;
    float s = 0.f;
    for (int j = 0; j < NN; ++j) s += adj[i * NN + j];
    FA[i] = s;
    AD[i] = adj[i * NN + i];
  }
  if (t < 32) {
    const float q = (float)(_Float16)(1.0f / 80.0f);
    WSUM[t] = ((t & 15) == 0) ? 6400.0f * q * q : 0.f;  // ||quantized x0||^2
  }
  __syncthreads();

  // ---- fill operand arrays + BCE loss over triu ----
  float lacc = 0.f;
  for (int f = t; f < NN * NN; f += NTHREADS) {
    const int r = f / NN, c = f - (f / NN) * NN;
    *(_Float16*)(XHb + r * 176 + c * 2) = (_Float16)(1.0f / 80.0f);  // x0[i=r][a=c]
    const float tv = (r == c) ? 0.f : recon[r * NN + c] * RD[r] * RD[c];
    // tgt[a=r][b=c], chunk-swizzled
    *(_Float16*)(TTb + r * 192 + (((c >> 3) ^ ((r >> 2) & 3)) * 16) +
                 (c & 7) * 2) = (_Float16)tv;
    *(float*)(DLb + (r * 84 + c) * 4) =
        AD[r] * RD[c] / (fabsf(FA[r] - FR[c]) + 1.f);                // DL[i=r][a=c]
    const float sv = (r == c) ? 0.f : adj[r * NN + c] * AD[r] * AD[c];
    *(_Float16*)(SRCHb + r * 208 + c * 2) = (_Float16)sv;            // SRCH[i=r][j=c]
    if (c >= r) {
      const float tb = adj[f], p = recon[f];
      lacc -= tb * logf(p) + (1.f - tb) * logf(1.f - p);
    }
  }
  // zero pads: SRCH j in [80,104); both MM buffers (8320 u32)
  for (int f = t; f < 1920; f += NTHREADS) {
    const int r = f / 24, j = 80 + (f - (f / 24) * 24);
    *(_Float16*)(SRCHb + r * 208 + j * 2) = (_Float16)0.f;
  }
  for (int f = t; f < 8320; f += NTHREADS) *(unsigned*)(MMb + f * 4) = 0u;

  #pragma unroll
  for (int off = 32; off > 0; off >>= 1) lacc += __shfl_down(lacc, off, 64);
  if (lane == 0) LSUM[wave] = lacc;
  __syncthreads();
  if (t == 0) {
    float s = 0.f;
    for (int w = 0; w < 16; ++w) s += LSUM[w];
    out[0] = s / 3240.f;  // 80*81/2
  }

  // ---- per-wave MFMA tile assignments ----
  const int i00 = (wave / 5) * 16, a00 = (wave % 5) * 16;
  const int tt1 = wave + 16;
  const bool has2 = tt1 < 25;
  const int i01 = has2 ? (tt1 / 5) * 16 : 0;
  const int a01 = has2 ? (tt1 % 5) * 16 : 0;

  // ---- phase-A mapping: 2 halves x 400 threads, 4x4 tiles, 40 b's each ----
  const int g = t >> 9;                 // b-half
  const int u = t & 511;
  const bool actA = (u < 400);
  const int rt = u / 20;                // 0..19 (4-row j-quads)
  const int ct = u - rt * 20;           // 0..19 (4-col a-tiles)
  const char* xrow = XHb + (rt * 4) * 176 + g * 80;   // x rows, b-half g
  const char* trow = TTb + (ct * 4) * 192;            // tgt rows (a), swizzled chunks
  const int tkey = ct & 3;              // == ((ct*4+c)>>2)&3 for all c<4
  // MM write base: phys j-block = (rt>>1)^(ct&3), 8B half rt&1
  char* mwp = MMb + g * 16640 + (ct * 4) * 208 +
              (((rt >> 1) ^ (ct & 3)) * 16) + ((rt & 1) * 8);

  // persistent x-old registers for phase B (lane la = i, 4 consecutive a)
  float xo0[4], xo1[4];
  #pragma unroll
  for (int k = 0; k < 4; ++k) xo0[k] = xo1[k] = (float)(_Float16)(1.0f / 80.0f);

  for (int it = 0; it < MITERS; ++it) {
    // ---- Phase A: MM_g[a][j] = max_{b in half} x[j,b]*tgt[a,b] ----
    if (actA) {
      unsigned m[4][4];
      #pragma unroll
      for (int r = 0; r < 4; ++r)
        #pragma unroll
        for (int c = 0; c < 4; ++c) m[r][c] = 0u;
      #pragma unroll
      for (int ch = 0; ch < 5; ++ch) {     // 5 x 8-b chunks in this half
        const uint4 xq0 = *(const uint4*)(xrow + 0 * 176 + ch * 16);
        const uint4 xq1 = *(const uint4*)(xrow + 1 * 176 + ch * 16);
        const uint4 xq2 = *(const uint4*)(xrow + 2 * 176 + ch * 16);
        const uint4 xq3 = *(const uint4*)(xrow + 3 * 176 + ch * 16);
        const int tco = (((g * 5 + ch) ^ tkey) * 16);
        #pragma unroll
        for (int c = 0; c < 4; ++c) {
          const uint4 tq = *(const uint4*)(trow + c * 192 + tco);
          m[0][c] = pk_max_f16(m[0][c], pk_mul_f16(xq0.x, tq.x));
          m[0][c] = pk_max_f16(m[0][c], pk_mul_f16(xq0.y, tq.y));
          m[0][c] = pk_max_f16(m[0][c], pk_mul_f16(xq0.z, tq.z));
          m[0][c] = pk_max_f16(m[0][c], pk_mul_f16(xq0.w, tq.w));
          m[1][c] = pk_max_f16(m[1][c], pk_mul_f16(xq1.x, tq.x));
          m[1][c] = pk_max_f16(m[1][c], pk_mul_f16(xq1.y, tq.y));
          m[1][c] = pk_max_f16(m[1][c], pk_mul_f16(xq1.z, tq.z));
          m[1][c] = pk_max_f16(m[1][c], pk_mul_f16(xq1.w, tq.w));
          m[2][c] = pk_max_f16(m[2][c], pk_mul_f16(xq2.x, tq.x));
          m[2][c] = pk_max_f16(m[2][c], pk_mul_f16(xq2.y, tq.y));
          m[2][c] = pk_max_f16(m[2][c], pk_mul_f16(xq2.z, tq.z));
          m[2][c] = pk_max_f16(m[2][c], pk_mul_f16(xq2.w, tq.w));
          m[3][c] = pk_max_f16(m[3][c], pk_mul_f16(xq3.x, tq.x));
          m[3][c] = pk_max_f16(m[3][c], pk_mul_f16(xq3.y, tq.y));
          m[3][c] = pk_max_f16(m[3][c], pk_mul_f16(xq3.z, tq.z));
          m[3][c] = pk_max_f16(m[3][c], pk_mul_f16(xq3.w, tq.w));
        }
      }
      #pragma unroll
      for (int c = 0; c < 4; ++c) {
        unsigned lo[4];
        #pragma unroll
        for (int r = 0; r < 4; ++r) {
          const unsigned v = m[r][c];
          lo[r] = pk_max_f16(v, (v >> 16) | (v << 16)) & 0xffffu;  // fold b-pair
        }
        *(uint2*)(mwp + c * 208) =
            make_uint2(lo[0] | (lo[1] << 16), lo[2] | (lo[3] << 16));
      }
    } else if (t == 1023) {
      // idle-in-A thread pre-sums the norm partials for this iteration
      const float* W = WSUM + ((it & 1) << 4);
      float s = 0.f;
      #pragma unroll
      for (int w = 0; w < 16; ++w) s += W[w];
      TOT[it & 1] = s;
    }
    __syncthreads();

    // ---- Phase B: x_new = inv * (x*d + SRC @ max(MM0,MM1)), transposed-C ----
    const float inv = 1.0f / sqrtf(TOT[it & 1]);

    float ss = 0.f;
    DO_TILE(i00, a00, xo0);
    if (has2) DO_TILE(i01, a01, xo1);

    // wave-64 sum via DPP (VALU-only), total in lane 63
    ss = dpp_add<0x111>(ss);  // row_shr:1
    ss = dpp_add<0x112>(ss);  // row_shr:2
    ss = dpp_add<0x114>(ss);  // row_shr:4
    ss = dpp_add<0x118>(ss);  // row_shr:8
    ss = dpp_add<0x142>(ss);  // row_bcast:15
    ss = dpp_add<0x143>(ss);  // row_bcast:31
    if (lane == 63) WSUM[(((it + 1) & 1) << 4) + wave] = ss;
    __syncthreads();
  }

  // ---- exact final normalization + output (out[1 + i*80 + a]) ----
  {
    const float* WF = WSUM + ((MITERS & 1) << 4);
    float tot = 0.f;
    #pragma unroll
    for (int w = 0; w < 16; ++w) tot += WF[w];
    const float finv = 1.0f / sqrtf(tot);
    for (int f = t; f < NN * NN; f += NTHREADS) {
      const int i = f / NN, a = f - (f / NN) * NN;
      out[1 + f] = (float)*(const _Float16*)(XHb + i * 176 + a * 2) * finv;
    }
  }
}

extern "C" void kernel_launch(void* const* d_in, const int* in_sizes, int n_in,
                              void* d_out, int out_size, void* d_ws, size_t ws_size,
                              hipStream_t stream) {
  const float* recon = (const float*)d_in[0];
  const float* adj   = (const float*)d_in[1];
  float* out = (float*)d_out;
  (void)in_sizes; (void)n_in; (void)out_size; (void)d_ws; (void)ws_size;

  (void)hipFuncSetAttribute(reinterpret_cast<const void*>(grf_kernel),
                            hipFuncAttributeMaxDynamicSharedMemorySize,
                            LDS_BYTES);
  grf_kernel<<<1, NTHREADS, LDS_BYTES, stream>>>(recon, adj, out);
}

// Round 12
// 338.477 us; speedup vs baseline: 1.3129x; 1.0357x over previous
//
#include <hip/hip_runtime.h>
#include <math.h>

#define NN 80
#define MITERS 50
#define NTHREADS 1024

typedef _Float16 h8 __attribute__((ext_vector_type(8)));
typedef float f4 __attribute__((ext_vector_type(4)));

__device__ __forceinline__ unsigned pk_mul_f16(unsigned a, unsigned b) {
  unsigned d; asm("v_pk_mul_f16 %0, %1, %2" : "=v"(d) : "v"(a), "v"(b)); return d;
}
__device__ __forceinline__ unsigned pk_max_f16(unsigned a, unsigned b) {
  unsigned d; asm("v_pk_max_f16 %0, %1, %2" : "=v"(d) : "v"(a), "v"(b)); return d;
}
__device__ __forceinline__ h8 as_h8(uint4 u) {
  union { uint4 u; h8 h; } x; x.u = u; return x.h;
}
// wave64 sum via DPP (VALU-only, frees the LDS pipe); ctrl must be constexpr
template <int CTRL>
__device__ __forceinline__ float dpp_add(float x) {
  int yi = __builtin_amdgcn_update_dpp(0, __builtin_bit_cast(int, x),
                                       CTRL, 0xf, 0xf, true);
  return x + __builtin_bit_cast(float, yi);
}

// ---- LDS byte offsets (16B-aligned) ----
// XH : fp16 [80][88]  row-major x[i][a], stride 176B
// TT : fp16 [80] rows of 256B, tgt[a][b]; 16B chunk c>>3 stored at
//      phys chunk (c>>3)^((a>>2)&7)  (10 logical chunks, 16 phys slots)
// MM : 2 bufs fp16 [80 a][104 j], stride 208B, j-block swizzle ^((a>>2)&3)
// SRCH: fp16 [80 i][104 j] (0/1), stride 208B, zero pad j>=80
// DL : f32 [80 i][84 a], stride 336B
#define OFF_XH    0
#define OFF_TT    14080
#define OFF_MM    34560
#define OFF_SRCH  67840
#define OFF_DL    84480
#define OFF_FR    111360
#define OFF_FA    111680
#define OFF_RD    112000
#define OFF_AD    112320
#define OFF_WSUM  112640    // 2 x 16 f32, double-buffered
#define OFF_TOT   112768    // 2 f32 (pre-summed norm)
#define OFF_LSUM  112784    // 16 f32
#define LDS_BYTES 112848    // 110.2 KiB < 160 KiB

// Phase-B MFMA C-tile, TRANSPOSED-C form; AF = preloaded A-fragments (uint4[3])
#define DO_TILE_P(I0, A0, XO, AF)                                             \
  {                                                                           \
    f4 acc = {0.f, 0.f, 0.f, 0.f};                                            \
    _Pragma("unroll")                                                         \
    for (int ks = 0; ks < 3; ++ks) {                                          \
      const int mo = ((A0) + la) * 208 + (((ks * 4 + gr) ^ mkey) * 16);       \
      const uint4 b0 = *(const uint4*)(MMb + mo);                             \
      const uint4 b1 = *(const uint4*)(MMb + 16640 + mo);                     \
      uint4 bb;                                                               \
      bb.x = pk_max_f16(b0.x, b1.x);                                          \
      bb.y = pk_max_f16(b0.y, b1.y);                                          \
      bb.z = pk_max_f16(b0.z, b1.z);                                          \
      bb.w = pk_max_f16(b0.w, b1.w);                                          \
      acc = __builtin_amdgcn_mfma_f32_16x16x32_f16(as_h8(bb),                 \
                                                   as_h8(AF[ks]), acc,        \
                                                   0, 0, 0);                  \
    }                                                                         \
    const int iN = (I0) + la;                                                 \
    const int ab = (A0) + gr * 4;                                             \
    const float4 dl = *(const float4*)(DLb + iN * 336 + ab * 4);              \
    const float n0 = fmaf(XO[0], dl.x, acc[0]) * inv;                         \
    const float n1 = fmaf(XO[1], dl.y, acc[1]) * inv;                         \
    const float n2 = fmaf(XO[2], dl.z, acc[2]) * inv;                         \
    const float n3 = fmaf(XO[3], dl.w, acc[3]) * inv;                         \
    ss += n0 * n0 + n1 * n1 + n2 * n2 + n3 * n3;                              \
    XO[0] = n0; XO[1] = n1; XO[2] = n2; XO[3] = n3;                           \
    const unsigned ulo = __builtin_bit_cast(                                  \
        unsigned, __builtin_amdgcn_cvt_pkrtz(n0, n1));                        \
    const unsigned uhi = __builtin_bit_cast(                                  \
        unsigned, __builtin_amdgcn_cvt_pkrtz(n2, n3));                        \
    *(uint2*)(XHb + iN * 176 + ab * 2) = make_uint2(ulo, uhi);                \
  }

// variant that re-reads A-fragments from LDS (second tile; saves VGPRs)
#define DO_TILE(I0, A0, XO)                                                   \
  {                                                                           \
    uint4 afr[3];                                                             \
    _Pragma("unroll")                                                         \
    for (int ks = 0; ks < 3; ++ks)                                            \
      afr[ks] =                                                               \
          *(const uint4*)(SRCHb + ((I0) + la) * 208 + ks * 64 + gr * 16);     \
    DO_TILE_P(I0, A0, XO, afr)                                                \
  }

__global__ void __launch_bounds__(NTHREADS, 4)
grf_kernel(const float* __restrict__ recon, const float* __restrict__ adj,
           float* __restrict__ out) {
  extern __shared__ char ldsb[];
  char* XHb = ldsb + OFF_XH;
  char* TTb = ldsb + OFF_TT;
  char* MMb = ldsb + OFF_MM;
  char* SRCHb = ldsb + OFF_SRCH;
  char* DLb = ldsb + OFF_DL;
  float* FR = (float*)(ldsb + OFF_FR);
  float* FA = (float*)(ldsb + OFF_FA);
  float* RD = (float*)(ldsb + OFF_RD);
  float* AD = (float*)(ldsb + OFF_AD);
  float* WSUM = (float*)(ldsb + OFF_WSUM);
  float* TOT = (float*)(ldsb + OFF_TOT);
  float* LSUM = (float*)(ldsb + OFF_LSUM);

  const int t = threadIdx.x;
  const int wave = t >> 6, lane = t & 63;
  const int la = lane & 15, gr = lane >> 4;
  const int mkey = (la >> 2) & 3;  // MM read-side swizzle key

  // ---- row sums + diagonals ----
  if (t < 80) {
    float s = 0.f;
    for (int b = 0; b < NN; ++b) s += recon[t * NN + b];
    FR[t] = s;
    RD[t] = recon[t * NN + t];
  } else if (t < 160) {
    const int i = t - 80;
    float s = 0.f;
    for (int j = 0; j < NN; ++j) s += adj[i * NN + j];
    FA[i] = s;
    AD[i] = adj[i * NN + i];
  }
  if (t < 32) {
    const float q = (float)(_Float16)(1.0f / 80.0f);
    WSUM[t] = ((t & 15) == 0) ? 6400.0f * q * q : 0.f;  // ||quantized x0||^2
  }
  __syncthreads();

  // ---- fill operand arrays + BCE loss over triu ----
  float lacc = 0.f;
  for (int f = t; f < NN * NN; f += NTHREADS) {
    const int r = f / NN, c = f - (f / NN) * NN;
    *(_Float16*)(XHb + r * 176 + c * 2) = (_Float16)(1.0f / 80.0f);  // x0[i=r][a=c]
    const float tv = (r == c) ? 0.f : recon[r * NN + c] * RD[r] * RD[c];
    // tgt[a=r][b=c], 8-deep chunk swizzle, 256B row stride
    *(_Float16*)(TTb + r * 256 + (((c >> 3) ^ ((r >> 2) & 7)) * 16) +
                 (c & 7) * 2) = (_Float16)tv;
    *(float*)(DLb + (r * 84 + c) * 4) =
        AD[r] * RD[c] / (fabsf(FA[r] - FR[c]) + 1.f);                // DL[i=r][a=c]
    const float sv = (r == c) ? 0.f : adj[r * NN + c] * AD[r] * AD[c];
    *(_Float16*)(SRCHb + r * 208 + c * 2) = (_Float16)sv;            // SRCH[i=r][j=c]
    if (c >= r) {
      const float tb = adj[f], p = recon[f];
      lacc -= tb * logf(p) + (1.f - tb) * logf(1.f - p);
    }
  }
  // zero pads: SRCH j in [80,104); both MM buffers (8320 u32)
  for (int f = t; f < 1920; f += NTHREADS) {
    const int r = f / 24, j = 80 + (f - (f / 24) * 24);
    *(_Float16*)(SRCHb + r * 208 + j * 2) = (_Float16)0.f;
  }
  for (int f = t; f < 8320; f += NTHREADS) *(unsigned*)(MMb + f * 4) = 0u;

  #pragma unroll
  for (int off = 32; off > 0; off >>= 1) lacc += __shfl_down(lacc, off, 64);
  if (lane == 0) LSUM[wave] = lacc;
  __syncthreads();
  if (t == 0) {
    float s = 0.f;
    for (int w = 0; w < 16; ++w) s += LSUM[w];
    out[0] = s / 3240.f;  // 80*81/2
  }

  // ---- per-wave MFMA tile assignments ----
  const int i00 = (wave / 5) * 16, a00 = (wave % 5) * 16;
  const int tt1 = wave + 16;
  const bool has2 = tt1 < 25;
  const int i01 = has2 ? (tt1 / 5) * 16 : 0;
  const int a01 = has2 ? (tt1 % 5) * 16 : 0;

  // persistent A-fragments for tile 1 (SRCH is static after the sync above)
  uint4 af0[3];
  #pragma unroll
  for (int ks = 0; ks < 3; ++ks)
    af0[ks] = *(const uint4*)(SRCHb + (i00 + la) * 208 + ks * 64 + gr * 16);

  // ---- phase-A mapping: 2 halves x 400 threads, 4x4 tiles, 40 b's each ----
  const int g = t >> 9;                 // b-half
  const int u = t & 511;
  const bool actA = (u < 400);
  const int rt = u / 20;                // 0..19 (4-row j-quads)
  const int ct = u - rt * 20;           // 0..19 (4-col a-tiles)
  const char* xrow = XHb + (rt * 4) * 176 + g * 80;   // x rows, b-half g
  const char* trow = TTb + (ct * 4) * 256;            // tgt rows (a), swizzled chunks
  const int tkey = ct & 7;              // == ((ct*4+c)>>2)&7 for all c<4
  // MM write base: phys j-block = (rt>>1)^(ct&3), 8B half rt&1
  char* mwp = MMb + g * 16640 + (ct * 4) * 208 +
              (((rt >> 1) ^ (ct & 3)) * 16) + ((rt & 1) * 8);

  // persistent x-old registers for phase B (lane la = i, 4 consecutive a)
  float xo0[4], xo1[4];
  #pragma unroll
  for (int k = 0; k < 4; ++k) xo0[k] = xo1[k] = (float)(_Float16)(1.0f / 80.0f);

  for (int it = 0; it < MITERS; ++it) {
    // ---- Phase A: MM_g[a][j] = max_{b in half} x[j,b]*tgt[a,b] ----
    if (actA) {
      unsigned m[4][4];
      #pragma unroll
      for (int r = 0; r < 4; ++r)
        #pragma unroll
        for (int c = 0; c < 4; ++c) m[r][c] = 0u;
      #pragma unroll
      for (int ch = 0; ch < 5; ++ch) {     // 5 x 8-b chunks in this half
        const uint4 xq0 = *(const uint4*)(xrow + 0 * 176 + ch * 16);
        const uint4 xq1 = *(const uint4*)(xrow + 1 * 176 + ch * 16);
        const uint4 xq2 = *(const uint4*)(xrow + 2 * 176 + ch * 16);
        const uint4 xq3 = *(const uint4*)(xrow + 3 * 176 + ch * 16);
        const int tco = (((g * 5 + ch) ^ tkey) * 16);
        #pragma unroll
        for (int c = 0; c < 4; ++c) {
          const uint4 tq = *(const uint4*)(trow + c * 256 + tco);
          m[0][c] = pk_max_f16(m[0][c], pk_mul_f16(xq0.x, tq.x));
          m[0][c] = pk_max_f16(m[0][c], pk_mul_f16(xq0.y, tq.y));
          m[0][c] = pk_max_f16(m[0][c], pk_mul_f16(xq0.z, tq.z));
          m[0][c] = pk_max_f16(m[0][c], pk_mul_f16(xq0.w, tq.w));
          m[1][c] = pk_max_f16(m[1][c], pk_mul_f16(xq1.x, tq.x));
          m[1][c] = pk_max_f16(m[1][c], pk_mul_f16(xq1.y, tq.y));
          m[1][c] = pk_max_f16(m[1][c], pk_mul_f16(xq1.z, tq.z));
          m[1][c] = pk_max_f16(m[1][c], pk_mul_f16(xq1.w, tq.w));
          m[2][c] = pk_max_f16(m[2][c], pk_mul_f16(xq2.x, tq.x));
          m[2][c] = pk_max_f16(m[2][c], pk_mul_f16(xq2.y, tq.y));
          m[2][c] = pk_max_f16(m[2][c], pk_mul_f16(xq2.z, tq.z));
          m[2][c] = pk_max_f16(m[2][c], pk_mul_f16(xq2.w, tq.w));
          m[3][c] = pk_max_f16(m[3][c], pk_mul_f16(xq3.x, tq.x));
          m[3][c] = pk_max_f16(m[3][c], pk_mul_f16(xq3.y, tq.y));
          m[3][c] = pk_max_f16(m[3][c], pk_mul_f16(xq3.z, tq.z));
          m[3][c] = pk_max_f16(m[3][c], pk_mul_f16(xq3.w, tq.w));
        }
      }
      #pragma unroll
      for (int c = 0; c < 4; ++c) {
        unsigned lo[4];
        #pragma unroll
        for (int r = 0; r < 4; ++r) {
          const unsigned v = m[r][c];
          lo[r] = pk_max_f16(v, (v >> 16) | (v << 16)) & 0xffffu;  // fold b-pair
        }
        *(uint2*)(mwp + c * 208) =
            make_uint2(lo[0] | (lo[1] << 16), lo[2] | (lo[3] << 16));
      }
    } else if (t == 1023) {
      // idle-in-A thread pre-sums the norm partials for this iteration
      const float* W = WSUM + ((it & 1) << 4);
      float s = 0.f;
      #pragma unroll
      for (int w = 0; w < 16; ++w) s += W[w];
      TOT[it & 1] = s;
    }
    __syncthreads();

    // ---- Phase B: x_new = inv * (x*d + SRC @ max(MM0,MM1)), transposed-C ----
    const float inv = 1.0f / sqrtf(TOT[it & 1]);

    float ss = 0.f;
    DO_TILE_P(i00, a00, xo0, af0);
    if (has2) DO_TILE(i01, a01, xo1);

    // wave-64 sum via DPP (VALU-only), total in lane 63
    ss = dpp_add<0x111>(ss);  // row_shr:1
    ss = dpp_add<0x112>(ss);  // row_shr:2
    ss = dpp_add<0x114>(ss);  // row_shr:4
    ss = dpp_add<0x118>(ss);  // row_shr:8
    ss = dpp_add<0x142>(ss);  // row_bcast:15
    ss = dpp_add<0x143>(ss);  // row_bcast:31
    if (lane == 63) WSUM[(((it + 1) & 1) << 4) + wave] = ss;
    __syncthreads();
  }

  // ---- exact final normalization + output (out[1 + i*80 + a]) ----
  {
    const float* WF = WSUM + ((MITERS & 1) << 4);
    float tot = 0.f;
    #pragma unroll
    for (int w = 0; w < 16; ++w) tot += WF[w];
    const float finv = 1.0f / sqrtf(tot);
    for (int f = t; f < NN * NN; f += NTHREADS) {
      const int i = f / NN, a = f - (f / NN) * NN;
      out[1 + f] = (float)*(const _Float16*)(XHb + i * 176 + a * 2) * finv;
    }
  }
}

extern "C" void kernel_launch(void* const* d_in, const int* in_sizes, int n_in,
                              void* d_out, int out_size, void* d_ws, size_t ws_size,
                              hipStream_t stream) {
  const float* recon = (const float*)d_in[0];
  const float* adj   = (const float*)d_in[1];
  float* out = (float*)d_out;
  (void)in_sizes; (void)n_in; (void)out_size; (void)d_ws; (void)ws_size;

  (void)hipFuncSetAttribute(reinterpret_cast<const void*>(grf_kernel),
                            hipFuncAttributeMaxDynamicSharedMemorySize,
                            LDS_BYTES);
  grf_kernel<<<1, NTHREADS, LDS_BYTES, stream>>>(recon, adj, out);
}